// Round 3
// baseline (41373.996 us; speedup 1.0000x reference)
//
#include <hip/hip_runtime.h>
#include <hip/hip_bf16.h>

#define B 8
#define NN 16383
#define INDIM 300
#define HDIM 512
#define EDIM 100

using bf16 = __hip_bfloat16;

__device__ __forceinline__ float sigmoidf_(float v) { return 1.0f / (1.0f + __expf(-v)); }
__device__ __forceinline__ float cload(const float* p) { return *p; }
__device__ __forceinline__ float cload(const bf16* p)  { return __bfloat162float(*p); }
__device__ __forceinline__ void  cstore(float* p, float v) { *p = v; }
__device__ __forceinline__ void  cstore(bf16* p,  float v) { *p = __float2bfloat16(v); }

// ---------------- leaf level: iou = X@Wioux^T + bioux + biouh; c=sig(i)*tanh(u); h=sig(o)*tanh(c)
template <typename CT>
__global__ __launch_bounds__(256) void leaf_kernel(
    const float* __restrict__ inputs,
    const float* __restrict__ Wioux, const float* __restrict__ bioux,
    const float* __restrict__ biouh,
    bf16* __restrict__ hbuf, CT* __restrict__ cbuf,
    int start, int nb)
{
    const int node = blockIdx.x;
    const int g = start + node;
    const int t = threadIdx.x;
    __shared__ float xs[B][INDIM];
    for (int idx = t; idx < B * INDIM; idx += 256) {
        int b = idx / INDIM, i = idx - b * INDIM;
        xs[b][i] = inputs[((size_t)b * NN + g) * INDIM + i];
    }
    __syncthreads();

    float acc[6][B];
#pragma unroll
    for (int cc = 0; cc < 6; ++cc)
#pragma unroll
        for (int b = 0; b < B; ++b) acc[cc][b] = 0.f;

    for (int k = 0; k < INDIM; ++k) {
        float w[6];
#pragma unroll
        for (int cc = 0; cc < 6; ++cc) w[cc] = Wioux[(size_t)(t + 256 * cc) * INDIM + k];
#pragma unroll
        for (int b = 0; b < B; ++b) {
            float xv = xs[b][k];
#pragma unroll
            for (int cc = 0; cc < 6; ++cc) acc[cc][b] += w[cc] * xv;
        }
    }

#pragma unroll
    for (int p = 0; p < 2; ++p) {
        int hcol = t + 256 * p;
        float bi = bioux[hcol] + biouh[hcol];
        float bo = bioux[hcol + 512] + biouh[hcol + 512];
        float bu = bioux[hcol + 1024] + biouh[hcol + 1024];
#pragma unroll
        for (int b = 0; b < B; ++b) {
            float iv = acc[p][b] + bi;
            float ov = acc[2 + p][b] + bo;
            float uv = acc[4 + p][b] + bu;
            float cv = sigmoidf_(iv) * tanhf(uv);
            float hv = sigmoidf_(ov) * tanhf(cv);
            size_t off = ((size_t)b * nb + node) * HDIM + hcol;
            hbuf[off] = __float2bfloat16(hv);
            cstore(&cbuf[off], cv);
        }
    }
}

// ---------------- fused internal level
template <typename CT>
__global__ __launch_bounds__(256) void level_kernel(
    const float* __restrict__ inputs, const float* __restrict__ edge_inputs,
    const float* __restrict__ Wioux, const float* __restrict__ bioux,
    const float* __restrict__ Wiouh, const float* __restrict__ biouh,
    const float* __restrict__ Wfx, const float* __restrict__ bfx,
    const float* __restrict__ Wfh, const float* __restrict__ bfh,
    const float* __restrict__ We, const float* __restrict__ be,
    const bf16* __restrict__ hprev, const CT* __restrict__ cprev,
    bf16* __restrict__ hcur, CT* __restrict__ ccur,
    int start, int n)
{
    const int node = blockIdx.x;
    const int g = start + node;
    const int t = threadIdx.x;
    const int nprev = 2 * n;

    __shared__ float xs[B][INDIM];        // 9.6 KB
    __shared__ float wcs[B][2][EDIM];     // 6.4 KB
    __shared__ bf16  hcs[B][2][HDIM];     // 16 KB
    __shared__ float hsum[B][HDIM];       // 16 KB

    for (int idx = t; idx < B * INDIM; idx += 256) {
        int b = idx / INDIM, i = idx - b * INDIM;
        xs[b][i] = inputs[((size_t)b * NN + g) * INDIM + i];
    }
    for (int idx = t; idx < B * 2 * EDIM; idx += 256) {
        int b = idx / (2 * EDIM), r = idx - b * 2 * EDIM;
        int kid = r / EDIM, e = r - kid * EDIM;
        wcs[b][kid][e] = edge_inputs[((size_t)b * NN + (2 * g + 1 + kid)) * EDIM + e];
    }
    for (int idx = t; idx < B * 2 * HDIM; idx += 256) {
        int b = idx / (2 * HDIM), r = idx - b * 2 * HDIM;
        int kid = r / HDIM, col = r - kid * HDIM;
        hcs[b][kid][col] = hprev[((size_t)b * nprev + (2 * node + kid)) * HDIM + col];
    }
    __syncthreads();

    float acc[6][B];
    float xf[2][B];
#pragma unroll
    for (int cc = 0; cc < 6; ++cc)
#pragma unroll
        for (int b = 0; b < B; ++b) acc[cc][b] = 0.f;
#pragma unroll
    for (int p = 0; p < 2; ++p)
#pragma unroll
        for (int b = 0; b < B; ++b) xf[p][b] = 0.f;

    for (int k = 0; k < INDIM; ++k) {
        float w[6], wf0, wf1;
#pragma unroll
        for (int cc = 0; cc < 6; ++cc) w[cc] = Wioux[(size_t)(t + 256 * cc) * INDIM + k];
        wf0 = Wfx[(size_t)t * INDIM + k];
        wf1 = Wfx[(size_t)(t + 256) * INDIM + k];
#pragma unroll
        for (int b = 0; b < B; ++b) {
            float xv = xs[b][k];
#pragma unroll
            for (int cc = 0; cc < 6; ++cc) acc[cc][b] += w[cc] * xv;
            xf[0][b] += wf0 * xv;
            xf[1][b] += wf1 * xv;
        }
    }
    {
        float bf0 = bfx[t], bf1 = bfx[t + 256];
#pragma unroll
        for (int b = 0; b < B; ++b) { xf[0][b] += bf0; xf[1][b] += bf1; }
    }

    float hs[2][B], fc[2][B];
#pragma unroll
    for (int p = 0; p < 2; ++p)
#pragma unroll
        for (int b = 0; b < B; ++b) { hs[p][b] = 0.f; fc[p][b] = 0.f; }

    for (int kid = 0; kid < 2; ++kid) {
        float exacc[2][B];
#pragma unroll
        for (int p = 0; p < 2; ++p)
#pragma unroll
            for (int b = 0; b < B; ++b) exacc[p][b] = 0.f;
        for (int e = 0; e < EDIM; ++e) {
            float w0 = We[(size_t)t * EDIM + e];
            float w1 = We[(size_t)(t + 256) * EDIM + e];
#pragma unroll
            for (int b = 0; b < B; ++b) {
                float wv = wcs[b][kid][e];
                exacc[0][b] += w0 * wv;
                exacc[1][b] += w1 * wv;
            }
        }
        float facc[2][B];
#pragma unroll
        for (int p = 0; p < 2; ++p)
#pragma unroll
            for (int b = 0; b < B; ++b) facc[p][b] = 0.f;
        for (int k = 0; k < HDIM; ++k) {
            float w0 = Wfh[(size_t)t * HDIM + k];
            float w1 = Wfh[(size_t)(t + 256) * HDIM + k];
#pragma unroll
            for (int b = 0; b < B; ++b) {
                float hv = __bfloat162float(hcs[b][kid][k]);
                facc[0][b] += w0 * hv;
                facc[1][b] += w1 * hv;
            }
        }
#pragma unroll
        for (int p = 0; p < 2; ++p) {
            int col = t + 256 * p;
            float bev = be[col], bfhv = bfh[col];
#pragma unroll
            for (int b = 0; b < B; ++b) {
                float ex = sigmoidf_(exacc[p][b] + bev);
                float f = sigmoidf_(facc[p][b] + bfhv + xf[p][b]);
                hs[p][b] += ex * __bfloat162float(hcs[b][kid][col]);
                fc[p][b] += f * cload(&cprev[((size_t)b * nprev + (2 * node + kid)) * HDIM + col]);
            }
        }
    }

#pragma unroll
    for (int p = 0; p < 2; ++p)
#pragma unroll
        for (int b = 0; b < B; ++b) hsum[b][t + 256 * p] = hs[p][b];
    __syncthreads();

    for (int k = 0; k < HDIM; ++k) {
        float w[6];
#pragma unroll
        for (int cc = 0; cc < 6; ++cc) w[cc] = Wiouh[(size_t)(t + 256 * cc) * HDIM + k];
#pragma unroll
        for (int b = 0; b < B; ++b) {
            float hv = hsum[b][k];
#pragma unroll
            for (int cc = 0; cc < 6; ++cc) acc[cc][b] += w[cc] * hv;
        }
    }

#pragma unroll
    for (int p = 0; p < 2; ++p) {
        int hcol = t + 256 * p;
        float bi = bioux[hcol] + biouh[hcol];
        float bo = bioux[hcol + 512] + biouh[hcol + 512];
        float bu = bioux[hcol + 1024] + biouh[hcol + 1024];
#pragma unroll
        for (int b = 0; b < B; ++b) {
            float iv = acc[p][b] + bi;
            float ov = acc[2 + p][b] + bo;
            float uv = acc[4 + p][b] + bu;
            float cv = sigmoidf_(iv) * tanhf(uv) + fc[p][b];
            float hv = sigmoidf_(ov) * tanhf(cv);
            size_t off = ((size_t)b * n + node) * HDIM + hcol;
            hcur[off] = __float2bfloat16(hv);
            cstore(&ccur[off], cv);
        }
    }
}

// ---------------- output: concat(c_root, h_root) per batch, as FP32 (harness reads f32!)
template <typename CT>
__global__ __launch_bounds__(256) void out_kernel(
    const bf16* __restrict__ hroot, const CT* __restrict__ croot,
    float* __restrict__ out)
{
    int t = blockIdx.x * 256 + threadIdx.x;
    if (t >= B * 2 * HDIM) return;
    int b = t / (2 * HDIM);
    int j = t - b * 2 * HDIM;
    float v;
    if (j < HDIM) v = cload(&croot[(size_t)b * HDIM + j]);
    else          v = __bfloat162float(hroot[(size_t)b * HDIM + (j - HDIM)]);
    out[t] = v;
}

__global__ void diag_kernel(float* out, float v) { out[0] = v; }

template <typename CT>
static bool run_tree(const float* inputs, const float* edge_inputs,
                     const float* Wioux, const float* bioux,
                     const float* Wiouh, const float* biouh,
                     const float* Wfx, const float* bfx,
                     const float* Wfh, const float* bfh,
                     const float* We, const float* be,
                     bf16* hA, CT* cA, bf16* hB, CT* cB,
                     float* out, hipStream_t stream)
{
    (void)hipGetLastError();  // clear stale state

    leaf_kernel<CT><<<8192, 256, 0, stream>>>(inputs, Wioux, bioux, biouh, hA, cA, 8191, 8192);
    if (hipGetLastError() != hipSuccess) {
        diag_kernel<<<1, 1, 0, stream>>>(out, 3.0e6f);
        return false;
    }

    bf16* h0 = hA; CT* c0 = cA;
    bf16* h1 = hB; CT* c1 = cB;
    for (int lvl = 12; lvl >= 0; --lvl) {
        int start = (1 << lvl) - 1;
        int n = 1 << lvl;
        level_kernel<CT><<<n, 256, 0, stream>>>(inputs, edge_inputs,
                                                Wioux, bioux, Wiouh, biouh,
                                                Wfx, bfx, Wfh, bfh, We, be,
                                                h0, c0, h1, c1, start, n);
        if (hipGetLastError() != hipSuccess) {
            diag_kernel<<<1, 1, 0, stream>>>(out, 2.0e6f + lvl * 1.0e4f);
            return false;
        }
        bf16* ht = h0; h0 = h1; h1 = ht;
        CT*   ct = c0; c0 = c1; c1 = ct;
    }
    out_kernel<CT><<<(B * 2 * HDIM + 255) / 256, 256, 0, stream>>>(h0, c0, out);
    return true;
}

extern "C" void kernel_launch(void* const* d_in, const int* in_sizes, int n_in,
                              void* d_out, int out_size, void* d_ws, size_t ws_size,
                              hipStream_t stream)
{
    const float* inputs      = (const float*)d_in[0];
    const float* edge_inputs = (const float*)d_in[1];
    const float* Wioux       = (const float*)d_in[2];
    const float* bioux       = (const float*)d_in[3];
    const float* Wiouh       = (const float*)d_in[4];
    const float* biouh       = (const float*)d_in[5];
    const float* Wfx         = (const float*)d_in[6];
    const float* bfx         = (const float*)d_in[7];
    const float* Wfh         = (const float*)d_in[8];
    const float* bfh         = (const float*)d_in[9];
    const float* We          = (const float*)d_in[10];
    const float* be          = (const float*)d_in[11];
    float* out = (float*)d_out;

    const size_t eA = (size_t)B * 8192 * HDIM;  // 33,554,432 elems
    const size_t eB = (size_t)B * 4096 * HDIM;  // 16,777,216 elems

    const size_t need_f32c  = (eA + eB) * (sizeof(bf16) + sizeof(float)); // ~302 MB
    const size_t need_bf16c = (eA + eB) * (2 * sizeof(bf16));             // ~201 MB

    if (ws_size >= need_f32c) {
        bf16* hA = (bf16*)d_ws;
        bf16* hB = hA + eA;
        float* cA = (float*)(hB + eB);
        float* cB = cA + eA;
        run_tree<float>(inputs, edge_inputs, Wioux, bioux, Wiouh, biouh,
                        Wfx, bfx, Wfh, bfh, We, be, hA, cA, hB, cB, out, stream);
    } else if (ws_size >= need_bf16c) {
        bf16* hA = (bf16*)d_ws;
        bf16* hB = hA + eA;
        bf16* cA = hB + eB;
        bf16* cB = cA + eA;
        run_tree<bf16>(inputs, edge_inputs, Wioux, bioux, Wiouh, biouh,
                       Wfx, bfx, Wfh, bfh, We, be, hA, cA, hB, cB, out, stream);
    } else {
        diag_kernel<<<1, 1, 0, stream>>>(out, 2.0e8f);
    }
}

// Round 4
// 9395.353 us; speedup vs baseline: 4.4037x; 4.4037x over previous
//
#include <hip/hip_runtime.h>
#include <hip/hip_bf16.h>

#define B 8
#define NN 16383
#define INDIM 300
#define HDIM 512
#define EDIM 100

using bf16 = __hip_bfloat16;

__device__ __forceinline__ float sigmoidf_(float v) { return 1.0f / (1.0f + __expf(-v)); }
__device__ __forceinline__ float cload(const float* p) { return *p; }
__device__ __forceinline__ float cload(const bf16* p)  { return __bfloat162float(*p); }
__device__ __forceinline__ void  cstore(float* p, float v) { *p = v; }
__device__ __forceinline__ void  cstore(bf16* p,  float v) { *p = __float2bfloat16(v); }

// ---------------- transpose: src[R][C] -> dst[C][R]
__global__ __launch_bounds__(256) void transpose_kernel(
    const float* __restrict__ src, float* __restrict__ dst, int R, int C)
{
    int idx = blockIdx.x * 256 + threadIdx.x;
    if (idx >= R * C) return;
    int r = idx / C, c = idx - r * C;
    dst[(size_t)c * R + r] = src[idx];
}

// ---------------- leaf: iou = X@Wioux^T + bioux + biouh; c=sig(i)*tanh(u); h=sig(o)*tanh(c)
// WiouxT is K-major: [INDIM][1536]
template <typename CT>
__global__ __launch_bounds__(256) void leaf_kernel(
    const float* __restrict__ inputs,
    const float* __restrict__ WiouxT, const float* __restrict__ bioux,
    const float* __restrict__ biouh,
    bf16* __restrict__ hbuf, CT* __restrict__ cbuf,
    int start, int nb)
{
    const int node = blockIdx.x;
    const int g = start + node;
    const int t = threadIdx.x;
    __shared__ float xs[B][INDIM];
    for (int idx = t; idx < B * INDIM; idx += 256) {
        int b = idx / INDIM, i = idx - b * INDIM;
        xs[b][i] = inputs[((size_t)b * NN + g) * INDIM + i];
    }
    __syncthreads();

    float acc[6][B];
#pragma unroll
    for (int cc = 0; cc < 6; ++cc)
#pragma unroll
        for (int b = 0; b < B; ++b) acc[cc][b] = 0.f;

#pragma unroll 4
    for (int k = 0; k < INDIM; ++k) {
        float w[6];
#pragma unroll
        for (int cc = 0; cc < 6; ++cc) w[cc] = WiouxT[(size_t)k * 1536 + t + 256 * cc];
#pragma unroll
        for (int b = 0; b < B; ++b) {
            float xv = xs[b][k];
#pragma unroll
            for (int cc = 0; cc < 6; ++cc) acc[cc][b] += w[cc] * xv;
        }
    }

#pragma unroll
    for (int p = 0; p < 2; ++p) {
        int hcol = t + 256 * p;
        float bi = bioux[hcol] + biouh[hcol];
        float bo = bioux[hcol + 512] + biouh[hcol + 512];
        float bu = bioux[hcol + 1024] + biouh[hcol + 1024];
#pragma unroll
        for (int b = 0; b < B; ++b) {
            float iv = acc[p][b] + bi;
            float ov = acc[2 + p][b] + bo;
            float uv = acc[4 + p][b] + bu;
            float cv = sigmoidf_(iv) * tanhf(uv);
            float hv = sigmoidf_(ov) * tanhf(cv);
            size_t off = ((size_t)b * nb + node) * HDIM + hcol;
            hbuf[off] = __float2bfloat16(hv);
            cstore(&cbuf[off], cv);
        }
    }
}

// ---------------- fused internal level (all weights K-major transposed)
template <typename CT>
__global__ __launch_bounds__(256) void level_kernel(
    const float* __restrict__ inputs, const float* __restrict__ edge_inputs,
    const float* __restrict__ WiouxT, const float* __restrict__ bioux,
    const float* __restrict__ WiouhT, const float* __restrict__ biouh,
    const float* __restrict__ WfxT, const float* __restrict__ bfx,
    const float* __restrict__ WfhT, const float* __restrict__ bfh,
    const float* __restrict__ WeT, const float* __restrict__ be,
    const bf16* __restrict__ hprev, const CT* __restrict__ cprev,
    bf16* __restrict__ hcur, CT* __restrict__ ccur,
    int start, int n)
{
    const int node = blockIdx.x;
    const int g = start + node;
    const int t = threadIdx.x;
    const int nprev = 2 * n;

    __shared__ float xs[B][INDIM];        // 9.6 KB
    __shared__ float wcs[B][2][EDIM];     // 6.4 KB
    __shared__ bf16  hcs[B][2][HDIM];     // 16 KB
    __shared__ float hsum[B][HDIM];       // 16 KB

    for (int idx = t; idx < B * INDIM; idx += 256) {
        int b = idx / INDIM, i = idx - b * INDIM;
        xs[b][i] = inputs[((size_t)b * NN + g) * INDIM + i];
    }
    for (int idx = t; idx < B * 2 * EDIM; idx += 256) {
        int b = idx / (2 * EDIM), r = idx - b * 2 * EDIM;
        int kid = r / EDIM, e = r - kid * EDIM;
        wcs[b][kid][e] = edge_inputs[((size_t)b * NN + (2 * g + 1 + kid)) * EDIM + e];
    }
    for (int idx = t; idx < B * 2 * HDIM; idx += 256) {
        int b = idx / (2 * HDIM), r = idx - b * 2 * HDIM;
        int kid = r / HDIM, col = r - kid * HDIM;
        hcs[b][kid][col] = hprev[((size_t)b * nprev + (2 * node + kid)) * HDIM + col];
    }
    __syncthreads();

    float acc[6][B];
    float xf[2][B];
#pragma unroll
    for (int cc = 0; cc < 6; ++cc)
#pragma unroll
        for (int b = 0; b < B; ++b) acc[cc][b] = 0.f;
#pragma unroll
    for (int p = 0; p < 2; ++p)
#pragma unroll
        for (int b = 0; b < B; ++b) xf[p][b] = 0.f;

#pragma unroll 2
    for (int k = 0; k < INDIM; ++k) {
        float w[6], wf0, wf1;
#pragma unroll
        for (int cc = 0; cc < 6; ++cc) w[cc] = WiouxT[(size_t)k * 1536 + t + 256 * cc];
        wf0 = WfxT[(size_t)k * 512 + t];
        wf1 = WfxT[(size_t)k * 512 + t + 256];
#pragma unroll
        for (int b = 0; b < B; ++b) {
            float xv = xs[b][k];
#pragma unroll
            for (int cc = 0; cc < 6; ++cc) acc[cc][b] += w[cc] * xv;
            xf[0][b] += wf0 * xv;
            xf[1][b] += wf1 * xv;
        }
    }
    {
        float bf0 = bfx[t], bf1 = bfx[t + 256];
#pragma unroll
        for (int b = 0; b < B; ++b) { xf[0][b] += bf0; xf[1][b] += bf1; }
    }

    float hs[2][B], fc[2][B];
#pragma unroll
    for (int p = 0; p < 2; ++p)
#pragma unroll
        for (int b = 0; b < B; ++b) { hs[p][b] = 0.f; fc[p][b] = 0.f; }

    for (int kid = 0; kid < 2; ++kid) {
        float exacc[2][B];
#pragma unroll
        for (int p = 0; p < 2; ++p)
#pragma unroll
            for (int b = 0; b < B; ++b) exacc[p][b] = 0.f;
#pragma unroll 2
        for (int e = 0; e < EDIM; ++e) {
            float w0 = WeT[(size_t)e * 512 + t];
            float w1 = WeT[(size_t)e * 512 + t + 256];
#pragma unroll
            for (int b = 0; b < B; ++b) {
                float wv = wcs[b][kid][e];
                exacc[0][b] += w0 * wv;
                exacc[1][b] += w1 * wv;
            }
        }
        float facc[2][B];
#pragma unroll
        for (int p = 0; p < 2; ++p)
#pragma unroll
            for (int b = 0; b < B; ++b) facc[p][b] = 0.f;
#pragma unroll 2
        for (int k = 0; k < HDIM; ++k) {
            float w0 = WfhT[(size_t)k * 512 + t];
            float w1 = WfhT[(size_t)k * 512 + t + 256];
#pragma unroll
            for (int b = 0; b < B; ++b) {
                float hv = __bfloat162float(hcs[b][kid][k]);
                facc[0][b] += w0 * hv;
                facc[1][b] += w1 * hv;
            }
        }
#pragma unroll
        for (int p = 0; p < 2; ++p) {
            int col = t + 256 * p;
            float bev = be[col], bfhv = bfh[col];
#pragma unroll
            for (int b = 0; b < B; ++b) {
                float ex = sigmoidf_(exacc[p][b] + bev);
                float f = sigmoidf_(facc[p][b] + bfhv + xf[p][b]);
                hs[p][b] += ex * __bfloat162float(hcs[b][kid][col]);
                fc[p][b] += f * cload(&cprev[((size_t)b * nprev + (2 * node + kid)) * HDIM + col]);
            }
        }
    }

#pragma unroll
    for (int p = 0; p < 2; ++p)
#pragma unroll
        for (int b = 0; b < B; ++b) hsum[b][t + 256 * p] = hs[p][b];
    __syncthreads();

#pragma unroll 2
    for (int k = 0; k < HDIM; ++k) {
        float w[6];
#pragma unroll
        for (int cc = 0; cc < 6; ++cc) w[cc] = WiouhT[(size_t)k * 1536 + t + 256 * cc];
#pragma unroll
        for (int b = 0; b < B; ++b) {
            float hv = hsum[b][k];
#pragma unroll
            for (int cc = 0; cc < 6; ++cc) acc[cc][b] += w[cc] * hv;
        }
    }

#pragma unroll
    for (int p = 0; p < 2; ++p) {
        int hcol = t + 256 * p;
        float bi = bioux[hcol] + biouh[hcol];
        float bo = bioux[hcol + 512] + biouh[hcol + 512];
        float bu = bioux[hcol + 1024] + biouh[hcol + 1024];
#pragma unroll
        for (int b = 0; b < B; ++b) {
            float iv = acc[p][b] + bi;
            float ov = acc[2 + p][b] + bo;
            float uv = acc[4 + p][b] + bu;
            float cv = sigmoidf_(iv) * tanhf(uv) + fc[p][b];
            float hv = sigmoidf_(ov) * tanhf(cv);
            size_t off = ((size_t)b * n + node) * HDIM + hcol;
            hcur[off] = __float2bfloat16(hv);
            cstore(&ccur[off], cv);
        }
    }
}

// ---------------- output: concat(c_root, h_root) per batch, FP32
template <typename CT>
__global__ __launch_bounds__(256) void out_kernel(
    const bf16* __restrict__ hroot, const CT* __restrict__ croot,
    float* __restrict__ out)
{
    int t = blockIdx.x * 256 + threadIdx.x;
    if (t >= B * 2 * HDIM) return;
    int b = t / (2 * HDIM);
    int j = t - b * 2 * HDIM;
    float v;
    if (j < HDIM) v = cload(&croot[(size_t)b * HDIM + j]);
    else          v = __bfloat162float(hroot[(size_t)b * HDIM + (j - HDIM)]);
    out[t] = v;
}

__global__ void diag_kernel(float* out, float v) { out[0] = v; }

template <typename CT>
static void run_tree(const float* inputs, const float* edge_inputs,
                     const float* WiouxT, const float* bioux,
                     const float* WiouhT, const float* biouh,
                     const float* WfxT, const float* bfx,
                     const float* WfhT, const float* bfh,
                     const float* WeT, const float* be,
                     bf16* hA, CT* cA, bf16* hB, CT* cB,
                     float* out, hipStream_t stream)
{
    leaf_kernel<CT><<<8192, 256, 0, stream>>>(inputs, WiouxT, bioux, biouh, hA, cA, 8191, 8192);

    bf16* h0 = hA; CT* c0 = cA;
    bf16* h1 = hB; CT* c1 = cB;
    for (int lvl = 12; lvl >= 0; --lvl) {
        int start = (1 << lvl) - 1;
        int n = 1 << lvl;
        level_kernel<CT><<<n, 256, 0, stream>>>(inputs, edge_inputs,
                                                WiouxT, bioux, WiouhT, biouh,
                                                WfxT, bfx, WfhT, bfh, WeT, be,
                                                h0, c0, h1, c1, start, n);
        bf16* ht = h0; h0 = h1; h1 = ht;
        CT*   ct = c0; c0 = c1; c1 = ct;
    }
    out_kernel<CT><<<(B * 2 * HDIM + 255) / 256, 256, 0, stream>>>(h0, c0, out);
}

extern "C" void kernel_launch(void* const* d_in, const int* in_sizes, int n_in,
                              void* d_out, int out_size, void* d_ws, size_t ws_size,
                              hipStream_t stream)
{
    const float* inputs      = (const float*)d_in[0];
    const float* edge_inputs = (const float*)d_in[1];
    const float* Wioux       = (const float*)d_in[2];
    const float* bioux       = (const float*)d_in[3];
    const float* Wiouh       = (const float*)d_in[4];
    const float* biouh       = (const float*)d_in[5];
    const float* Wfx         = (const float*)d_in[6];
    const float* bfx         = (const float*)d_in[7];
    const float* Wfh         = (const float*)d_in[8];
    const float* bfh         = (const float*)d_in[9];
    const float* We          = (const float*)d_in[10];
    const float* be          = (const float*)d_in[11];
    float* out = (float*)d_out;

    // transposed weight sizes (floats)
    const size_t szWioux = (size_t)1536 * INDIM;   // 460800
    const size_t szWfx   = (size_t)512 * INDIM;    // 153600
    const size_t szWiouh = (size_t)1536 * HDIM;    // 786432
    const size_t szWfh   = (size_t)512 * HDIM;     // 262144
    const size_t szWe    = (size_t)512 * EDIM;     // 51200
    const size_t wt_elems = szWioux + szWfx + szWiouh + szWfh + szWe; // 1,714,176

    const size_t eA = (size_t)B * 8192 * HDIM;  // 33,554,432 elems
    const size_t eB = (size_t)B * 4096 * HDIM;  // 16,777,216 elems

    const size_t need_f32c  = wt_elems * 4 + (eA + eB) * (sizeof(bf16) + sizeof(float)); // ~309 MB
    const size_t need_bf16c = wt_elems * 4 + (eA + eB) * (2 * sizeof(bf16));             // ~208 MB

    float* WiouxT = (float*)d_ws;
    float* WfxT   = WiouxT + szWioux;
    float* WiouhT = WfxT + szWfx;
    float* WfhT   = WiouhT + szWiouh;
    float* WeT    = WfhT + szWfh;
    char*  bufs   = (char*)(WeT + szWe);

    if (ws_size < need_bf16c) {
        diag_kernel<<<1, 1, 0, stream>>>(out, 2.0e8f);
        return;
    }

    // pack transposed weights (runs every call; ~7 MB total, trivial cost)
    transpose_kernel<<<(int)((szWioux + 255) / 256), 256, 0, stream>>>(Wioux, WiouxT, 1536, INDIM);
    transpose_kernel<<<(int)((szWfx   + 255) / 256), 256, 0, stream>>>(Wfx,   WfxT,   512,  INDIM);
    transpose_kernel<<<(int)((szWiouh + 255) / 256), 256, 0, stream>>>(Wiouh, WiouhT, 1536, HDIM);
    transpose_kernel<<<(int)((szWfh   + 255) / 256), 256, 0, stream>>>(Wfh,   WfhT,   512,  HDIM);
    transpose_kernel<<<(int)((szWe    + 255) / 256), 256, 0, stream>>>(We,    WeT,    512,  EDIM);

    if (ws_size >= need_f32c) {
        bf16* hA = (bf16*)bufs;
        bf16* hB = hA + eA;
        float* cA = (float*)(hB + eB);
        float* cB = cA + eA;
        run_tree<float>(inputs, edge_inputs, WiouxT, bioux, WiouhT, biouh,
                        WfxT, bfx, WfhT, bfh, WeT, be, hA, cA, hB, cB, out, stream);
    } else {
        bf16* hA = (bf16*)bufs;
        bf16* hB = hA + eA;
        bf16* cA = hB + eB;
        bf16* cB = cA + eA;
        run_tree<bf16>(inputs, edge_inputs, WiouxT, bioux, WiouhT, biouh,
                       WfxT, bfx, WfhT, bfh, WeT, be, hA, cA, hB, cB, out, stream);
    }
}

// Round 5
// 7851.592 us; speedup vs baseline: 5.2695x; 1.1966x over previous
//
#include <hip/hip_runtime.h>
#include <hip/hip_bf16.h>
#include <stdint.h>

#define B 8
#define NN 16383
#define INDIM 300
#define HDIM 512
#define EDIM 100

typedef short bf16x8 __attribute__((ext_vector_type(8)));
typedef float f32x4 __attribute__((ext_vector_type(4)));
typedef unsigned short ushort_t;

__device__ __forceinline__ float sigmoidf_(float v) { return 1.0f / (1.0f + __expf(-v)); }

__device__ __forceinline__ ushort_t f2b(float f) {
    union { float f; unsigned int u; } x; x.f = f;
    unsigned int u = x.u;
    return (ushort_t)((u + 0x7FFFu + ((u >> 16) & 1u)) >> 16);
}
__device__ __forceinline__ float b2f(ushort_t s) {
    union { float f; unsigned int u; } x; x.u = ((unsigned int)s) << 16; return x.f;
}
__device__ __forceinline__ bf16x8 zero8() {
    bf16x8 v;
#pragma unroll
    for (int i = 0; i < 8; ++i) v[i] = 0;
    return v;
}

// ---------------- pack weights into MFMA B-fragment order.
// W: [N][Kdim] row-major fp32 (N = ntiles*16). out entry idx=(nt*Kt+kt)*64+lane
// holds 8 bf16: B[k][n] = W[n][k], n = nt*16+(lane&15), k = kt*32+(lane>>4)*8+i.
__global__ __launch_bounds__(256) void pack_kernel(
    const float* __restrict__ W, ushort_t* __restrict__ out,
    int Kdim, int Kt, int total)
{
    int idx = blockIdx.x * 256 + threadIdx.x;
    if (idx >= total) return;
    int lane = idx & 63;
    int kt = (idx >> 6) % Kt;
    int nt = idx / (Kt << 6);
    int n = nt * 16 + (lane & 15);
    int kb = kt * 32 + (lane >> 4) * 8;
    ushort_t v[8];
#pragma unroll
    for (int i = 0; i < 8; ++i) {
        int k = kb + i;
        v[i] = (k < Kdim) ? f2b(W[(size_t)n * Kdim + k]) : (ushort_t)0;
    }
    *reinterpret_cast<uint4*>(out + (size_t)idx * 8) = *reinterpret_cast<const uint4*>(v);
}

// ---------------- K1 "children": per block 4 parents.
// xf = x@Wfx^T (K=320), ex = sig(wc@We^T+be) (K=128), f = sig(hc@Wfh^T+bfh+xf) (K=512)
// h_sum = sum_kid ex*hc -> hY (bf16); fc = sum_kid f*cc -> cY (bf16)
__global__ __launch_bounds__(256) void children_kernel(
    const float* __restrict__ inputs, const float* __restrict__ edge_inputs,
    const ushort_t* __restrict__ pWfx, const float* __restrict__ bfx,
    const ushort_t* __restrict__ pWfh, const float* __restrict__ bfh,
    const ushort_t* __restrict__ pWe,  const float* __restrict__ be,
    const ushort_t* __restrict__ hX, const ushort_t* __restrict__ cX,
    ushort_t* __restrict__ hY, ushort_t* __restrict__ cY,
    int start, int n)
{
    const int nb = blockIdx.x * 4;
    const int t = threadIdx.x;
    const int w = t >> 6, lane = t & 63;
    const int kr = lane >> 4, cl = lane & 15;
    const int nprev = 2 * n;

    __shared__ ushort_t xs[32][328];   // 32 rows (p*8+b) x K320(+pad)
    __shared__ ushort_t wc[64][136];   // 64 rows (kid*32+p*8+b) x K128(+pad)

    for (int idx = t; idx < 32 * 328; idx += 256) {
        int r = idx / 328, k = idx - r * 328;
        int p = r >> 3, b = r & 7;
        int g = start + nb + p;
        float v = (k < INDIM && (nb + p) < n) ? inputs[((size_t)b * NN + g) * INDIM + k] : 0.f;
        xs[r][k] = f2b(v);
    }
    for (int idx = t; idx < 64 * 136; idx += 256) {
        int r = idx / 136, e = idx - r * 136;
        int kid = r >> 5, pr = r & 31;
        int p = pr >> 3, b = pr & 7;
        int child = 2 * (start + nb + p) + 1 + kid;
        float v = (e < EDIM && (nb + p) < n) ? edge_inputs[((size_t)b * NN + child) * EDIM + e] : 0.f;
        wc[r][e] = f2b(v);
    }
    __syncthreads();

    const bf16x8* fWfx = reinterpret_cast<const bf16x8*>(pWfx);
    const bf16x8* fWfh = reinterpret_cast<const bf16x8*>(pWfh);
    const bf16x8* fWe  = reinterpret_cast<const bf16x8*>(pWe);

    // per-lane A addresses for the f GEMM (rows = mt*16+cl)
    bool rvalid[2];
    size_t abase[2][2];  // [kid][mt]
#pragma unroll
    for (int mt = 0; mt < 2; ++mt) {
        int prow = mt * 16 + cl;
        int p = prow >> 3, b = prow & 7;
        rvalid[mt] = (nb + p) < n;
#pragma unroll
        for (int kid = 0; kid < 2; ++kid)
            abase[kid][mt] = ((size_t)b * nprev + 2 * (nb + p) + kid) * HDIM + kr * 8;
    }

#pragma unroll 1
    for (int j = 0; j < 8; ++j) {
        const int nt = w * 8 + j;
        const int col = nt * 16 + cl;
        f32x4 xfa[2], exa[2][2], fa[2][2];
#pragma unroll
        for (int mt = 0; mt < 2; ++mt) {
#pragma unroll
            for (int r = 0; r < 4; ++r) {
                xfa[mt][r] = 0.f;
                exa[0][mt][r] = 0.f; exa[1][mt][r] = 0.f;
                fa[0][mt][r] = 0.f;  fa[1][mt][r] = 0.f;
            }
        }
        // xf: K=320 over xs
#pragma unroll
        for (int kt = 0; kt < 10; ++kt) {
            bf16x8 bf_ = fWfx[(size_t)(nt * 10 + kt) * 64 + lane];
#pragma unroll
            for (int mt = 0; mt < 2; ++mt) {
                bf16x8 a = *reinterpret_cast<const bf16x8*>(&xs[mt * 16 + cl][kt * 32 + kr * 8]);
                xfa[mt] = __builtin_amdgcn_mfma_f32_16x16x32_bf16(a, bf_, xfa[mt], 0, 0, 0);
            }
        }
        // ex: K=128 over wc
#pragma unroll
        for (int kt = 0; kt < 4; ++kt) {
            bf16x8 bf_ = fWe[(size_t)(nt * 4 + kt) * 64 + lane];
#pragma unroll
            for (int kid = 0; kid < 2; ++kid)
#pragma unroll
            for (int mt = 0; mt < 2; ++mt) {
                bf16x8 a = *reinterpret_cast<const bf16x8*>(&wc[kid * 32 + mt * 16 + cl][kt * 32 + kr * 8]);
                exa[kid][mt] = __builtin_amdgcn_mfma_f32_16x16x32_bf16(a, bf_, exa[kid][mt], 0, 0, 0);
            }
        }
        // f: K=512 over children h (global bf16)
#pragma unroll 2
        for (int kt = 0; kt < 16; ++kt) {
            bf16x8 bf_ = fWfh[(size_t)(nt * 16 + kt) * 64 + lane];
#pragma unroll
            for (int kid = 0; kid < 2; ++kid)
#pragma unroll
            for (int mt = 0; mt < 2; ++mt) {
                bf16x8 a = rvalid[mt]
                    ? *reinterpret_cast<const bf16x8*>(hX + abase[kid][mt] + kt * 32)
                    : zero8();
                fa[kid][mt] = __builtin_amdgcn_mfma_f32_16x16x32_bf16(a, bf_, fa[kid][mt], 0, 0, 0);
            }
        }
        // epilogue
        const float bfxv = bfx[col], bev = be[col], bfhv = bfh[col];
#pragma unroll
        for (int mt = 0; mt < 2; ++mt) {
#pragma unroll
            for (int r = 0; r < 4; ++r) {
                int prow = mt * 16 + kr * 4 + r;
                int p = prow >> 3, b = prow & 7;
                if (nb + p >= n) continue;
                float xfv = xfa[mt][r] + bfxv;
                float hterm = 0.f, fcterm = 0.f;
#pragma unroll
                for (int kid = 0; kid < 2; ++kid) {
                    float exv = sigmoidf_(exa[kid][mt][r] + bev);
                    float fv  = sigmoidf_(fa[kid][mt][r] + bfhv + xfv);
                    size_t coff = ((size_t)b * nprev + 2 * (nb + p) + kid) * HDIM + col;
                    hterm  += exv * b2f(hX[coff]);
                    fcterm += fv  * b2f(cX[coff]);
                }
                size_t o = ((size_t)b * n + nb + p) * HDIM + col;
                hY[o] = f2b(hterm);
                cY[o] = f2b(fcterm);
            }
        }
    }
}

// ---------------- K2 "iou" (also leaf): per block 16 nodes (M=128).
// iou = x@Wioux^T (+ hsum@Wiouh^T for levels) + biases; c = sig(i)tanh(u) (+fc); h = sig(o)tanh(c)
template <bool LEAF>
__global__ __launch_bounds__(256) void iou_kernel(
    const float* __restrict__ inputs,
    const ushort_t* __restrict__ pWioux, const float* __restrict__ bioux,
    const ushort_t* __restrict__ pWiouh, const float* __restrict__ biouh,
    const ushort_t* __restrict__ hYsum, const ushort_t* __restrict__ cYfc,
    ushort_t* __restrict__ hOut, ushort_t* __restrict__ cOut,
    int start, int n)
{
    const int nb = blockIdx.x * 16;
    const int t = threadIdx.x;
    const int w = t >> 6, lane = t & 63;
    const int kr = lane >> 4, cl = lane & 15;
    const int NKT = LEAF ? 10 : 26;

    __shared__ ushort_t chunk[128][40];

    const bf16x8* fWx = reinterpret_cast<const bf16x8*>(pWioux);
    const bf16x8* fWh = reinterpret_cast<const bf16x8*>(pWiouh);

    const int srow = t >> 1, shalf = t & 1;   // staging: row, 16-col half
    const int sp = srow >> 3, sb = srow & 7;
    const int sg = start + nb + sp;

#pragma unroll 1
    for (int j = 0; j < 8; ++j) {
        const int cnt = j * 4 + w;
        f32x4 acc[8][3];
#pragma unroll
        for (int mt = 0; mt < 8; ++mt)
#pragma unroll
            for (int q = 0; q < 3; ++q)
#pragma unroll
                for (int r = 0; r < 4; ++r) acc[mt][q][r] = 0.f;

#pragma unroll 1
        for (int kt = 0; kt < NKT; ++kt) {
            __syncthreads();
            {
                ushort_t vv[16];
                if (kt < 10) {
                    int k0 = kt * 32 + shalf * 16;
#pragma unroll
                    for (int q = 0; q < 4; ++q) {
                        int k = k0 + q * 4;
                        float4 xv = make_float4(0.f, 0.f, 0.f, 0.f);
                        if (k + 4 <= INDIM)
                            xv = *reinterpret_cast<const float4*>(&inputs[((size_t)sb * NN + sg) * INDIM + k]);
                        vv[q * 4 + 0] = f2b(xv.x); vv[q * 4 + 1] = f2b(xv.y);
                        vv[q * 4 + 2] = f2b(xv.z); vv[q * 4 + 3] = f2b(xv.w);
                    }
                } else {
                    int k0 = (kt - 10) * 32 + shalf * 16;
                    uint4 u0 = make_uint4(0u, 0u, 0u, 0u), u1 = u0;
                    if (nb + sp < n) {
                        const ushort_t* src = hYsum + ((size_t)sb * n + nb + sp) * HDIM + k0;
                        u0 = *reinterpret_cast<const uint4*>(src);
                        u1 = *reinterpret_cast<const uint4*>(src + 8);
                    }
                    *reinterpret_cast<uint4*>(vv)     = u0;
                    *reinterpret_cast<uint4*>(vv + 8) = u1;
                }
                *reinterpret_cast<uint4*>(&chunk[srow][shalf * 16])     = *reinterpret_cast<const uint4*>(vv);
                *reinterpret_cast<uint4*>(&chunk[srow][shalf * 16 + 8]) = *reinterpret_cast<const uint4*>(vv + 8);
            }
            __syncthreads();

            bf16x8 av[8];
#pragma unroll
            for (int mt = 0; mt < 8; ++mt)
                av[mt] = *reinterpret_cast<const bf16x8*>(&chunk[mt * 16 + cl][kr * 8]);
#pragma unroll
            for (int q = 0; q < 3; ++q) {
                int ntile = q * 32 + cnt;
                bf16x8 bf_ = (kt < 10)
                    ? fWx[(size_t)(ntile * 10 + kt) * 64 + lane]
                    : fWh[(size_t)(ntile * 16 + (kt - 10)) * 64 + lane];
#pragma unroll
                for (int mt = 0; mt < 8; ++mt)
                    acc[mt][q] = __builtin_amdgcn_mfma_f32_16x16x32_bf16(av[mt], bf_, acc[mt][q], 0, 0, 0);
            }
        }

        // epilogue for this column tile
        const int col = cnt * 16 + cl;
        const float bi = bioux[col]        + biouh[col];
        const float bo = bioux[col + 512]  + biouh[col + 512];
        const float bu = bioux[col + 1024] + biouh[col + 1024];
#pragma unroll
        for (int mt = 0; mt < 8; ++mt) {
#pragma unroll
            for (int r = 0; r < 4; ++r) {
                int row = mt * 16 + kr * 4 + r;
                int p = row >> 3, b = row & 7;
                if (nb + p >= n) continue;
                float iv = acc[mt][0][r] + bi;
                float ov = acc[mt][1][r] + bo;
                float uv = acc[mt][2][r] + bu;
                size_t o = ((size_t)b * n + nb + p) * HDIM + col;
                float fc = LEAF ? 0.f : b2f(cYfc[o]);
                float cv = sigmoidf_(iv) * tanhf(uv) + fc;
                float hv = sigmoidf_(ov) * tanhf(cv);
                hOut[o] = f2b(hv);
                cOut[o] = f2b(cv);
            }
        }
    }
}

// ---------------- output: concat(c_root, h_root) per batch, FP32
__global__ __launch_bounds__(256) void out_kernel(
    const ushort_t* __restrict__ hroot, const ushort_t* __restrict__ croot,
    float* __restrict__ out)
{
    int t = blockIdx.x * 256 + threadIdx.x;
    if (t >= B * 2 * HDIM) return;
    int b = t / (2 * HDIM);
    int j = t - b * 2 * HDIM;
    float v;
    if (j < HDIM) v = b2f(croot[(size_t)b * HDIM + j]);
    else          v = b2f(hroot[(size_t)b * HDIM + (j - HDIM)]);
    out[t] = v;
}

__global__ void diag_kernel(float* out, float v) { out[0] = v; }

extern "C" void kernel_launch(void* const* d_in, const int* in_sizes, int n_in,
                              void* d_out, int out_size, void* d_ws, size_t ws_size,
                              hipStream_t stream)
{
    const float* inputs      = (const float*)d_in[0];
    const float* edge_inputs = (const float*)d_in[1];
    const float* Wioux       = (const float*)d_in[2];
    const float* bioux       = (const float*)d_in[3];
    const float* Wiouh       = (const float*)d_in[4];
    const float* biouh       = (const float*)d_in[5];
    const float* Wfx         = (const float*)d_in[6];
    const float* bfx         = (const float*)d_in[7];
    const float* Wfh         = (const float*)d_in[8];
    const float* bfh         = (const float*)d_in[9];
    const float* We          = (const float*)d_in[10];
    const float* be          = (const float*)d_in[11];
    float* out = (float*)d_out;

    // packed weight element counts (ushort)
    const size_t szWioux = (size_t)96 * 10 * 64 * 8;  // 491520
    const size_t szWfx   = (size_t)32 * 10 * 64 * 8;  // 163840
    const size_t szWe    = (size_t)32 * 4  * 64 * 8;  // 65536
    const size_t szWfh   = (size_t)32 * 16 * 64 * 8;  // 262144
    const size_t szWiouh = (size_t)96 * 16 * 64 * 8;  // 786432

    const size_t eX = (size_t)B * 8192 * HDIM;        // 33,554,432
    const size_t eY = (size_t)B * 4096 * HDIM;        // 16,777,216

    const size_t need = (szWioux + szWfx + szWe + szWfh + szWiouh
                         + 2 * eX + 2 * eY) * sizeof(ushort_t);  // ~204.9 MB
    if (ws_size < need) {
        diag_kernel<<<1, 1, 0, stream>>>(out, 2.0e8f);
        return;
    }

    ushort_t* p = (ushort_t*)d_ws;
    ushort_t* pWioux = p;            p += szWioux;
    ushort_t* pWfx   = p;            p += szWfx;
    ushort_t* pWe    = p;            p += szWe;
    ushort_t* pWfh   = p;            p += szWfh;
    ushort_t* pWiouh = p;            p += szWiouh;
    ushort_t* hX = p;                p += eX;
    ushort_t* cX = p;                p += eX;
    ushort_t* hY = p;                p += eY;
    ushort_t* cY = p;                p += eY;

    // pack weights
    pack_kernel<<<(int)((96 * 10 * 64 + 255) / 256), 256, 0, stream>>>(Wioux, pWioux, INDIM, 10, 96 * 10 * 64);
    pack_kernel<<<(int)((32 * 10 * 64 + 255) / 256), 256, 0, stream>>>(Wfx,   pWfx,   INDIM, 10, 32 * 10 * 64);
    pack_kernel<<<(int)((32 * 4  * 64 + 255) / 256), 256, 0, stream>>>(We,    pWe,    EDIM,  4,  32 * 4  * 64);
    pack_kernel<<<(int)((32 * 16 * 64 + 255) / 256), 256, 0, stream>>>(Wfh,   pWfh,   HDIM,  16, 32 * 16 * 64);
    pack_kernel<<<(int)((96 * 16 * 64 + 255) / 256), 256, 0, stream>>>(Wiouh, pWiouh, HDIM,  16, 96 * 16 * 64);

    // leaf level: start=8191, n=8192
    iou_kernel<true><<<512, 256, 0, stream>>>(inputs, pWioux, bioux, pWiouh, biouh,
                                              hY, cY, hX, cX, 8191, 8192);

    for (int lvl = 12; lvl >= 0; --lvl) {
        int start = (1 << lvl) - 1;
        int n = 1 << lvl;
        children_kernel<<<(n + 3) / 4, 256, 0, stream>>>(
            inputs, edge_inputs, pWfx, bfx, pWfh, bfh, pWe, be,
            hX, cX, hY, cY, start, n);
        iou_kernel<false><<<(n + 15) / 16, 256, 0, stream>>>(
            inputs, pWioux, bioux, pWiouh, biouh,
            hY, cY, hX, cX, start, n);
    }

    out_kernel<<<(B * 2 * HDIM + 255) / 256, 256, 0, stream>>>(hX, cX, out);
}

// Round 6
// 7750.813 us; speedup vs baseline: 5.3380x; 1.0130x over previous
//
#include <hip/hip_runtime.h>
#include <hip/hip_bf16.h>
#include <stdint.h>

#define B 8
#define NN 16383
#define INDIM 300
#define HDIM 512
#define EDIM 100

typedef short bf16x8 __attribute__((ext_vector_type(8)));
typedef float f32x4 __attribute__((ext_vector_type(4)));
typedef unsigned short ushort_t;

__device__ __forceinline__ float sigmoidf_(float v) { return 1.0f / (1.0f + __expf(-v)); }

__device__ __forceinline__ ushort_t f2b(float f) {
    union { float f; unsigned int u; } x; x.f = f;
    unsigned int u = x.u;
    return (ushort_t)((u + 0x7FFFu + ((u >> 16) & 1u)) >> 16);
}
__device__ __forceinline__ float b2f(ushort_t s) {
    union { float f; unsigned int u; } x; x.u = ((unsigned int)s) << 16; return x.f;
}
__device__ __forceinline__ bf16x8 zero8() {
    bf16x8 v;
#pragma unroll
    for (int i = 0; i < 8; ++i) v[i] = 0;
    return v;
}

// ---------------- pack weights into MFMA B-fragment order.
// W: [N][Kdim] row-major fp32 (N = ntiles*16). out entry idx=(nt*Kt+kt)*64+lane
// holds 8 bf16: B[k][n] = W[n][k], n = nt*16+(lane&15), k = kt*32+(lane>>4)*8+i.
__global__ __launch_bounds__(256) void pack_kernel(
    const float* __restrict__ W, ushort_t* __restrict__ out,
    int Kdim, int Kt, int total)
{
    int idx = blockIdx.x * 256 + threadIdx.x;
    if (idx >= total) return;
    int lane = idx & 63;
    int kt = (idx >> 6) % Kt;
    int nt = idx / (Kt << 6);
    int n = nt * 16 + (lane & 15);
    int kb = kt * 32 + (lane >> 4) * 8;
    ushort_t v[8];
#pragma unroll
    for (int i = 0; i < 8; ++i) {
        int k = kb + i;
        v[i] = (k < Kdim) ? f2b(W[(size_t)n * Kdim + k]) : (ushort_t)0;
    }
    *reinterpret_cast<uint4*>(out + (size_t)idx * 8) = *reinterpret_cast<const uint4*>(v);
}

// ---------------- K1 "children": per block 4 parents.
// xf = x@Wfx^T (K=320), ex = sig(wc@We^T+be) (K=128), f = sig(hc@Wfh^T+bfh+xf) (K=512)
// h_sum = sum_kid ex*hc -> hY (bf16); fc = sum_kid f*cc -> cY (bf16)
__global__ __launch_bounds__(256) void children_kernel(
    const float* __restrict__ inputs, const float* __restrict__ edge_inputs,
    const ushort_t* __restrict__ pWfx, const float* __restrict__ bfx,
    const ushort_t* __restrict__ pWfh, const float* __restrict__ bfh,
    const ushort_t* __restrict__ pWe,  const float* __restrict__ be,
    const ushort_t* __restrict__ hX, const ushort_t* __restrict__ cX,
    ushort_t* __restrict__ hY, ushort_t* __restrict__ cY,
    int start, int n)
{
    const int nb = blockIdx.x * 4;
    const int t = threadIdx.x;
    const int w = t >> 6, lane = t & 63;
    const int kr = lane >> 4, cl = lane & 15;
    const int nprev = 2 * n;

    __shared__ ushort_t xs[32][328];   // 32 rows (p*8+b) x K320(+pad)
    __shared__ ushort_t wc[64][136];   // 64 rows (kid*32+p*8+b) x K128(+pad)

    for (int idx = t; idx < 32 * 328; idx += 256) {
        int r = idx / 328, k = idx - r * 328;
        int p = r >> 3, b = r & 7;
        int g = start + nb + p;
        float v = (k < INDIM && (nb + p) < n) ? inputs[((size_t)b * NN + g) * INDIM + k] : 0.f;
        xs[r][k] = f2b(v);
    }
    for (int idx = t; idx < 64 * 136; idx += 256) {
        int r = idx / 136, e = idx - r * 136;
        int kid = r >> 5, pr = r & 31;
        int p = pr >> 3, b = pr & 7;
        int child = 2 * (start + nb + p) + 1 + kid;
        float v = (e < EDIM && (nb + p) < n) ? edge_inputs[((size_t)b * NN + child) * EDIM + e] : 0.f;
        wc[r][e] = f2b(v);
    }
    __syncthreads();

    const bf16x8* fWfx = reinterpret_cast<const bf16x8*>(pWfx);
    const bf16x8* fWfh = reinterpret_cast<const bf16x8*>(pWfh);
    const bf16x8* fWe  = reinterpret_cast<const bf16x8*>(pWe);

    // per-lane A addresses for the f GEMM (rows = mt*16+cl)
    bool rvalid[2];
    size_t abase[2][2];  // [kid][mt]
#pragma unroll
    for (int mt = 0; mt < 2; ++mt) {
        int prow = mt * 16 + cl;
        int p = prow >> 3, b = prow & 7;
        rvalid[mt] = (nb + p) < n;
#pragma unroll
        for (int kid = 0; kid < 2; ++kid)
            abase[kid][mt] = ((size_t)b * nprev + 2 * (nb + p) + kid) * HDIM + kr * 8;
    }

#pragma unroll 1
    for (int j = 0; j < 8; ++j) {
        const int nt = w * 8 + j;
        const int col = nt * 16 + cl;
        f32x4 xfa[2], exa[2][2], fa[2][2];
#pragma unroll
        for (int mt = 0; mt < 2; ++mt) {
#pragma unroll
            for (int r = 0; r < 4; ++r) {
                xfa[mt][r] = 0.f;
                exa[0][mt][r] = 0.f; exa[1][mt][r] = 0.f;
                fa[0][mt][r] = 0.f;  fa[1][mt][r] = 0.f;
            }
        }
        // xf: K=320 over xs
#pragma unroll
        for (int kt = 0; kt < 10; ++kt) {
            bf16x8 bf_ = fWfx[(size_t)(nt * 10 + kt) * 64 + lane];
#pragma unroll
            for (int mt = 0; mt < 2; ++mt) {
                bf16x8 a = *reinterpret_cast<const bf16x8*>(&xs[mt * 16 + cl][kt * 32 + kr * 8]);
                xfa[mt] = __builtin_amdgcn_mfma_f32_16x16x32_bf16(a, bf_, xfa[mt], 0, 0, 0);
            }
        }
        // ex: K=128 over wc
#pragma unroll
        for (int kt = 0; kt < 4; ++kt) {
            bf16x8 bf_ = fWe[(size_t)(nt * 4 + kt) * 64 + lane];
#pragma unroll
            for (int kid = 0; kid < 2; ++kid)
#pragma unroll
            for (int mt = 0; mt < 2; ++mt) {
                bf16x8 a = *reinterpret_cast<const bf16x8*>(&wc[kid * 32 + mt * 16 + cl][kt * 32 + kr * 8]);
                exa[kid][mt] = __builtin_amdgcn_mfma_f32_16x16x32_bf16(a, bf_, exa[kid][mt], 0, 0, 0);
            }
        }
        // f: K=512 over children h (global bf16)
#pragma unroll 2
        for (int kt = 0; kt < 16; ++kt) {
            bf16x8 bf_ = fWfh[(size_t)(nt * 16 + kt) * 64 + lane];
#pragma unroll
            for (int kid = 0; kid < 2; ++kid)
#pragma unroll
            for (int mt = 0; mt < 2; ++mt) {
                bf16x8 a = rvalid[mt]
                    ? *reinterpret_cast<const bf16x8*>(hX + abase[kid][mt] + kt * 32)
                    : zero8();
                fa[kid][mt] = __builtin_amdgcn_mfma_f32_16x16x32_bf16(a, bf_, fa[kid][mt], 0, 0, 0);
            }
        }
        // epilogue
        const float bfxv = bfx[col], bev = be[col], bfhv = bfh[col];
#pragma unroll
        for (int mt = 0; mt < 2; ++mt) {
#pragma unroll
            for (int r = 0; r < 4; ++r) {
                int prow = mt * 16 + kr * 4 + r;
                int p = prow >> 3, b = prow & 7;
                if (nb + p >= n) continue;
                float xfv = xfa[mt][r] + bfxv;
                float hterm = 0.f, fcterm = 0.f;
#pragma unroll
                for (int kid = 0; kid < 2; ++kid) {
                    float exv = sigmoidf_(exa[kid][mt][r] + bev);
                    float fv  = sigmoidf_(fa[kid][mt][r] + bfhv + xfv);
                    size_t coff = ((size_t)b * nprev + 2 * (nb + p) + kid) * HDIM + col;
                    hterm  += exv * b2f(hX[coff]);
                    fcterm += fv  * b2f(cX[coff]);
                }
                size_t o = ((size_t)b * n + nb + p) * HDIM + col;
                hY[o] = f2b(hterm);
                cY[o] = f2b(fcterm);
            }
        }
    }
}

// ---------------- K2 "iou" (also leaf): per block 16 nodes (M=128).
// iou = x@Wioux^T (+ hsum@Wiouh^T for levels) + biases; c = sig(i)tanh(u) (+fc); h = sig(o)tanh(c)
template <bool LEAF>
__global__ __launch_bounds__(256) void iou_kernel(
    const float* __restrict__ inputs,
    const ushort_t* __restrict__ pWioux, const float* __restrict__ bioux,
    const ushort_t* __restrict__ pWiouh, const float* __restrict__ biouh,
    const ushort_t* __restrict__ hYsum, const ushort_t* __restrict__ cYfc,
    ushort_t* __restrict__ hOut, ushort_t* __restrict__ cOut,
    int start, int n)
{
    const int nb = blockIdx.x * 16;
    const int t = threadIdx.x;
    const int w = t >> 6, lane = t & 63;
    const int kr = lane >> 4, cl = lane & 15;
    const int NKT = LEAF ? 10 : 26;

    __shared__ ushort_t chunk[128][40];

    const bf16x8* fWx = reinterpret_cast<const bf16x8*>(pWioux);
    const bf16x8* fWh = reinterpret_cast<const bf16x8*>(pWiouh);

    const int srow = t >> 1, shalf = t & 1;   // staging: row, 16-col half
    const int sp = srow >> 3, sb = srow & 7;
    const int sg = start + nb + sp;

#pragma unroll 1
    for (int j = 0; j < 8; ++j) {
        const int cnt = j * 4 + w;
        f32x4 acc[8][3];
#pragma unroll
        for (int mt = 0; mt < 8; ++mt)
#pragma unroll
            for (int q = 0; q < 3; ++q)
#pragma unroll
                for (int r = 0; r < 4; ++r) acc[mt][q][r] = 0.f;

#pragma unroll 1
        for (int kt = 0; kt < NKT; ++kt) {
            __syncthreads();
            {
                ushort_t vv[16];
                if (kt < 10) {
                    int k0 = kt * 32 + shalf * 16;
#pragma unroll
                    for (int q = 0; q < 4; ++q) {
                        int k = k0 + q * 4;
                        float4 xv = make_float4(0.f, 0.f, 0.f, 0.f);
                        if (k + 4 <= INDIM)
                            xv = *reinterpret_cast<const float4*>(&inputs[((size_t)sb * NN + sg) * INDIM + k]);
                        vv[q * 4 + 0] = f2b(xv.x); vv[q * 4 + 1] = f2b(xv.y);
                        vv[q * 4 + 2] = f2b(xv.z); vv[q * 4 + 3] = f2b(xv.w);
                    }
                } else {
                    int k0 = (kt - 10) * 32 + shalf * 16;
                    uint4 u0 = make_uint4(0u, 0u, 0u, 0u), u1 = u0;
                    if (nb + sp < n) {
                        const ushort_t* src = hYsum + ((size_t)sb * n + nb + sp) * HDIM + k0;
                        u0 = *reinterpret_cast<const uint4*>(src);
                        u1 = *reinterpret_cast<const uint4*>(src + 8);
                    }
                    *reinterpret_cast<uint4*>(vv)     = u0;
                    *reinterpret_cast<uint4*>(vv + 8) = u1;
                }
                *reinterpret_cast<uint4*>(&chunk[srow][shalf * 16])     = *reinterpret_cast<const uint4*>(vv);
                *reinterpret_cast<uint4*>(&chunk[srow][shalf * 16 + 8]) = *reinterpret_cast<const uint4*>(vv + 8);
            }
            __syncthreads();

            bf16x8 av[8];
#pragma unroll
            for (int mt = 0; mt < 8; ++mt)
                av[mt] = *reinterpret_cast<const bf16x8*>(&chunk[mt * 16 + cl][kr * 8]);
#pragma unroll
            for (int q = 0; q < 3; ++q) {
                int ntile = q * 32 + cnt;
                bf16x8 bf_ = (kt < 10)
                    ? fWx[(size_t)(ntile * 10 + kt) * 64 + lane]
                    : fWh[(size_t)(ntile * 16 + (kt - 10)) * 64 + lane];
#pragma unroll
                for (int mt = 0; mt < 8; ++mt)
                    acc[mt][q] = __builtin_amdgcn_mfma_f32_16x16x32_bf16(av[mt], bf_, acc[mt][q], 0, 0, 0);
            }
        }

        // epilogue for this column tile
        const int col = cnt * 16 + cl;
        const float bi = bioux[col]        + biouh[col];
        const float bo = bioux[col + 512]  + biouh[col + 512];
        const float bu = bioux[col + 1024] + biouh[col + 1024];
#pragma unroll
        for (int mt = 0; mt < 8; ++mt) {
#pragma unroll
            for (int r = 0; r < 4; ++r) {
                int row = mt * 16 + kr * 4 + r;
                int p = row >> 3, b = row & 7;
                if (nb + p >= n) continue;
                float iv = acc[mt][0][r] + bi;
                float ov = acc[mt][1][r] + bo;
                float uv = acc[mt][2][r] + bu;
                size_t o = ((size_t)b * n + nb + p) * HDIM + col;
                float fc = LEAF ? 0.f : b2f(cYfc[o]);
                float cv = sigmoidf_(iv) * tanhf(uv) + fc;
                float hv = sigmoidf_(ov) * tanhf(cv);
                hOut[o] = f2b(hv);
                cOut[o] = f2b(cv);
            }
        }
    }
}

// ---------------- output: concat(c_root, h_root) per batch, FP32
__global__ __launch_bounds__(256) void out_kernel(
    const ushort_t* __restrict__ hroot, const ushort_t* __restrict__ croot,
    float* __restrict__ out)
{
    int t = blockIdx.x * 256 + threadIdx.x;
    if (t >= B * 2 * HDIM) return;
    int b = t / (2 * HDIM);
    int j = t - b * 2 * HDIM;
    float v;
    if (j < HDIM) v = b2f(croot[(size_t)b * HDIM + j]);
    else          v = b2f(hroot[(size_t)b * HDIM + (j - HDIM)]);
    out[t] = v;
}

__global__ void diag_kernel(float* out, float v) { out[0] = v; }

extern "C" void kernel_launch(void* const* d_in, const int* in_sizes, int n_in,
                              void* d_out, int out_size, void* d_ws, size_t ws_size,
                              hipStream_t stream)
{
    const float* inputs      = (const float*)d_in[0];
    const float* edge_inputs = (const float*)d_in[1];
    const float* Wioux       = (const float*)d_in[2];
    const float* bioux       = (const float*)d_in[3];
    const float* Wiouh       = (const float*)d_in[4];
    const float* biouh       = (const float*)d_in[5];
    const float* Wfx         = (const float*)d_in[6];
    const float* bfx         = (const float*)d_in[7];
    const float* Wfh         = (const float*)d_in[8];
    const float* bfh         = (const float*)d_in[9];
    const float* We          = (const float*)d_in[10];
    const float* be          = (const float*)d_in[11];
    float* out = (float*)d_out;

    // packed weight element counts (ushort)
    const size_t szWioux = (size_t)96 * 10 * 64 * 8;  // 491520
    const size_t szWfx   = (size_t)32 * 10 * 64 * 8;  // 163840
    const size_t szWe    = (size_t)32 * 4  * 64 * 8;  // 65536
    const size_t szWfh   = (size_t)32 * 16 * 64 * 8;  // 262144
    const size_t szWiouh = (size_t)96 * 16 * 64 * 8;  // 786432

    const size_t eX = (size_t)B * 8192 * HDIM;        // 33,554,432
    const size_t eY = (size_t)B * 4096 * HDIM;        // 16,777,216

    const size_t need = (szWioux + szWfx + szWe + szWfh + szWiouh
                         + 2 * eX + 2 * eY) * sizeof(ushort_t);  // ~204.9 MB
    if (ws_size < need) {
        diag_kernel<<<1, 1, 0, stream>>>(out, 2.0e8f);
        return;
    }

    ushort_t* p = (ushort_t*)d_ws;
    ushort_t* pWioux = p;            p += szWioux;
    ushort_t* pWfx   = p;            p += szWfx;
    ushort_t* pWe    = p;            p += szWe;
    ushort_t* pWfh   = p;            p += szWfh;
    ushort_t* pWiouh = p;            p += szWiouh;
    ushort_t* hX = p;                p += eX;
    ushort_t* cX = p;                p += eX;
    ushort_t* hY = p;                p += eY;
    ushort_t* cY = p;                p += eY;

    // pack weights
    pack_kernel<<<(int)((96 * 10 * 64 + 255) / 256), 256, 0, stream>>>(Wioux, pWioux, INDIM, 10, 96 * 10 * 64);
    pack_kernel<<<(int)((32 * 10 * 64 + 255) / 256), 256, 0, stream>>>(Wfx,   pWfx,   INDIM, 10, 32 * 10 * 64);
    pack_kernel<<<(int)((32 * 4  * 64 + 255) / 256), 256, 0, stream>>>(We,    pWe,    EDIM,  4,  32 * 4  * 64);
    pack_kernel<<<(int)((32 * 16 * 64 + 255) / 256), 256, 0, stream>>>(Wfh,   pWfh,   HDIM,  16, 32 * 16 * 64);
    pack_kernel<<<(int)((96 * 16 * 64 + 255) / 256), 256, 0, stream>>>(Wiouh, pWiouh, HDIM,  16, 96 * 16 * 64);

    // leaf level: start=8191, n=8192
    iou_kernel<true><<<512, 256, 0, stream>>>(inputs, pWioux, bioux, pWiouh, biouh,
                                              hY, cY, hX, cX, 8191, 8192);

    for (int lvl = 12; lvl >= 0; --lvl) {
        int start = (1 << lvl) - 1;
        int n = 1 << lvl;
        children_kernel<<<(n + 3) / 4, 256, 0, stream>>>(
            inputs, edge_inputs, pWfx, bfx, pWfh, bfh, pWe, be,
            hX, cX, hY, cY, start, n);
        iou_kernel<false><<<(n + 15) / 16, 256, 0, stream>>>(
            inputs, pWioux, bioux, pWiouh, biouh,
            hY, cY, hX, cX, start, n);
    }

    out_kernel<<<(B * 2 * HDIM + 255) / 256, 256, 0, stream>>>(hX, cX, out);
}

// Round 7
// 4818.832 us; speedup vs baseline: 8.5859x; 1.6084x over previous
//
#include <hip/hip_runtime.h>
#include <hip/hip_bf16.h>
#include <stdint.h>

#define B 8
#define NN 16383
#define INDIM 300
#define HDIM 512
#define EDIM 100

typedef short bf16x8 __attribute__((ext_vector_type(8)));
typedef float f32x4 __attribute__((ext_vector_type(4)));
typedef unsigned short ushort_t;

__device__ __forceinline__ float sigmoidf_(float v) { return 1.0f / (1.0f + __expf(-v)); }

__device__ __forceinline__ ushort_t f2b(float f) {
    union { float f; unsigned int u; } x; x.f = f;
    unsigned int u = x.u;
    return (ushort_t)((u + 0x7FFFu + ((u >> 16) & 1u)) >> 16);
}
__device__ __forceinline__ float b2f(ushort_t s) {
    union { float f; unsigned int u; } x; x.u = ((unsigned int)s) << 16; return x.f;
}
__device__ __forceinline__ bf16x8 zero8() {
    bf16x8 v;
#pragma unroll
    for (int i = 0; i < 8; ++i) v[i] = 0;
    return v;
}

// ---------------- pack weights into MFMA B-fragment order.
// W: [N][Kdim] row-major fp32 (N = ntiles*16). out entry idx=(nt*Kt+kt)*64+lane
// holds 8 bf16: B[k][n] = W[n][k], n = nt*16+(lane&15), k = kt*32+(lane>>4)*8+i.
__global__ __launch_bounds__(256) void pack_kernel(
    const float* __restrict__ W, ushort_t* __restrict__ out,
    int Kdim, int Kt, int total)
{
    int idx = blockIdx.x * 256 + threadIdx.x;
    if (idx >= total) return;
    int lane = idx & 63;
    int kt = (idx >> 6) % Kt;
    int nt = idx / (Kt << 6);
    int n = nt * 16 + (lane & 15);
    int kb = kt * 32 + (lane >> 4) * 8;
    ushort_t v[8];
#pragma unroll
    for (int i = 0; i < 8; ++i) {
        int k = kb + i;
        v[i] = (k < Kdim) ? f2b(W[(size_t)n * Kdim + k]) : (ushort_t)0;
    }
    *reinterpret_cast<uint4*>(out + (size_t)idx * 8) = *reinterpret_cast<const uint4*>(v);
}

// ---------------- children v2: 4 parents/block, 3 phases, no barriers after staging.
// rows (xf): p*8+b (32).  rows (ex/f): kid*32 + p*8 + b (64).
__global__ __launch_bounds__(256) void children_kernel(
    const float* __restrict__ inputs, const float* __restrict__ edge_inputs,
    const ushort_t* __restrict__ pWfx, const float* __restrict__ bfx,
    const ushort_t* __restrict__ pWfh, const float* __restrict__ bfh,
    const ushort_t* __restrict__ pWe,  const float* __restrict__ be,
    const ushort_t* __restrict__ hX, const ushort_t* __restrict__ cX,
    ushort_t* __restrict__ hY, ushort_t* __restrict__ cY,
    int start, int n)
{
    const int nb = blockIdx.x * 4;
    const int t = threadIdx.x;
    const int w = t >> 6, lane = t & 63;
    const int kr = lane >> 4, cl = lane & 15;
    const int nprev = 2 * n;

    __shared__ ushort_t xs[32][344];   // 21.5 KB, odd bank stride
    __shared__ ushort_t wc[64][136];   // 17 KB
    __shared__ ushort_t xfs[32][512];  // 32 KB (same-thread write/read)

    for (int idx = t; idx < 32 * 344; idx += 256) {
        int r = idx / 344, k = idx - r * 344;
        int p = r >> 3, b = r & 7;
        int g = start + nb + p;
        float v = (k < INDIM && (nb + p) < n) ? inputs[((size_t)b * NN + g) * INDIM + k] : 0.f;
        xs[r][k] = f2b(v);
    }
    for (int idx = t; idx < 64 * 136; idx += 256) {
        int r = idx / 136, e = idx - r * 136;
        int kid = r >> 5, pr = r & 31;
        int p = pr >> 3, b = pr & 7;
        int child = 2 * (start + nb + p) + 1 + kid;
        float v = (e < EDIM && (nb + p) < n) ? edge_inputs[((size_t)b * NN + child) * EDIM + e] : 0.f;
        wc[r][e] = f2b(v);
    }
    __syncthreads();

    const bf16x8* fWfx = reinterpret_cast<const bf16x8*>(pWfx);
    const bf16x8* fWfh = reinterpret_cast<const bf16x8*>(pWfh);
    const bf16x8* fWe  = reinterpret_cast<const bf16x8*>(pWe);

    // ---- Phase A: xf = x@Wfx^T + bfx -> xfs (bf16)
#pragma unroll 1
    for (int j = 0; j < 8; ++j) {
        const int nt = w * 8 + j;
        f32x4 a0, a1;
#pragma unroll
        for (int r = 0; r < 4; ++r) { a0[r] = 0.f; a1[r] = 0.f; }
#pragma unroll
        for (int kt = 0; kt < 10; ++kt) {
            bf16x8 bf_ = fWfx[(size_t)(nt * 10 + kt) * 64 + lane];
            bf16x8 av0 = *reinterpret_cast<const bf16x8*>(&xs[cl][kt * 32 + kr * 8]);
            bf16x8 av1 = *reinterpret_cast<const bf16x8*>(&xs[16 + cl][kt * 32 + kr * 8]);
            a0 = __builtin_amdgcn_mfma_f32_16x16x32_bf16(av0, bf_, a0, 0, 0, 0);
            a1 = __builtin_amdgcn_mfma_f32_16x16x32_bf16(av1, bf_, a1, 0, 0, 0);
        }
        const int col = nt * 16 + cl;
        const float bv = bfx[col];
#pragma unroll
        for (int r = 0; r < 4; ++r) {
            xfs[kr * 4 + r][col]      = f2b(a0[r] + bv);
            xfs[16 + kr * 4 + r][col] = f2b(a1[r] + bv);
        }
    }

    // ---- Phase B: ex = sig(wc@We^T + be); hY = sum_kid ex*hc
#pragma unroll 1
    for (int pp = 0; pp < 2; ++pp) {
        f32x4 acc[4][4];  // [q(nt)][mt]
#pragma unroll
        for (int q = 0; q < 4; ++q)
#pragma unroll
            for (int mt = 0; mt < 4; ++mt)
#pragma unroll
                for (int r = 0; r < 4; ++r) acc[q][mt][r] = 0.f;
#pragma unroll
        for (int kt = 0; kt < 4; ++kt) {
            bf16x8 av[4];
#pragma unroll
            for (int mt = 0; mt < 4; ++mt)
                av[mt] = *reinterpret_cast<const bf16x8*>(&wc[mt * 16 + cl][kt * 32 + kr * 8]);
#pragma unroll
            for (int q = 0; q < 4; ++q) {
                int nt = w * 8 + pp * 4 + q;
                bf16x8 bf_ = fWe[(size_t)(nt * 4 + kt) * 64 + lane];
#pragma unroll
                for (int mt = 0; mt < 4; ++mt)
                    acc[q][mt] = __builtin_amdgcn_mfma_f32_16x16x32_bf16(av[mt], bf_, acc[q][mt], 0, 0, 0);
            }
        }
#pragma unroll
        for (int q = 0; q < 4; ++q) {
            const int nt = w * 8 + pp * 4 + q;
            const int col = nt * 16 + cl;
            const float bev = be[col];
#pragma unroll
            for (int mh = 0; mh < 2; ++mh) {
#pragma unroll
                for (int r = 0; r < 4; ++r) {
                    int prow = mh * 16 + kr * 4 + r;
                    int p = prow >> 3, b = prow & 7;
                    if (nb + p >= n) continue;
                    float ex0 = sigmoidf_(acc[q][mh][r] + bev);      // kid 0 (Mt mh)
                    float ex1 = sigmoidf_(acc[q][mh + 2][r] + bev);  // kid 1 (Mt mh+2)
                    size_t c0 = ((size_t)b * nprev + 2 * (nb + p)) * HDIM + col;
                    float hterm = ex0 * b2f(hX[c0]) + ex1 * b2f(hX[c0 + HDIM]);
                    hY[((size_t)b * n + nb + p) * HDIM + col] = f2b(hterm);
                }
            }
        }
    }

    // ---- Phase C: f = sig(hc@Wfh^T + bfh + xf); cY = sum_kid f*cc
    bool avalid[4]; size_t abase[4];
#pragma unroll
    for (int mt = 0; mt < 4; ++mt) {
        int kid = mt >> 1;
        int prow = (mt & 1) * 16 + cl;
        int p = prow >> 3, b = prow & 7;
        avalid[mt] = (nb + p) < n;
        abase[mt] = ((size_t)b * nprev + 2 * (nb + p) + kid) * HDIM;
    }
#pragma unroll 1
    for (int pp = 0; pp < 2; ++pp) {
        f32x4 acc[4][4];  // [q(nt)][mt]
#pragma unroll
        for (int q = 0; q < 4; ++q)
#pragma unroll
            for (int mt = 0; mt < 4; ++mt)
#pragma unroll
                for (int r = 0; r < 4; ++r) acc[q][mt][r] = 0.f;
#pragma unroll 2
        for (int kt = 0; kt < 16; ++kt) {
            bf16x8 av[4];
#pragma unroll
            for (int mt = 0; mt < 4; ++mt)
                av[mt] = avalid[mt]
                    ? *reinterpret_cast<const bf16x8*>(hX + abase[mt] + kt * 32 + kr * 8)
                    : zero8();
#pragma unroll
            for (int q = 0; q < 4; ++q) {
                int nt = w * 8 + pp * 4 + q;
                bf16x8 bf_ = fWfh[(size_t)(nt * 16 + kt) * 64 + lane];
#pragma unroll
                for (int mt = 0; mt < 4; ++mt)
                    acc[q][mt] = __builtin_amdgcn_mfma_f32_16x16x32_bf16(av[mt], bf_, acc[q][mt], 0, 0, 0);
            }
        }
#pragma unroll
        for (int q = 0; q < 4; ++q) {
            const int nt = w * 8 + pp * 4 + q;
            const int col = nt * 16 + cl;
            const float bfhv = bfh[col];
#pragma unroll
            for (int mh = 0; mh < 2; ++mh) {
#pragma unroll
                for (int r = 0; r < 4; ++r) {
                    int prow = mh * 16 + kr * 4 + r;
                    int p = prow >> 3, b = prow & 7;
                    if (nb + p >= n) continue;
                    float xfv = b2f(xfs[prow][col]);
                    float f0 = sigmoidf_(acc[q][mh][r] + bfhv + xfv);
                    float f1 = sigmoidf_(acc[q][mh + 2][r] + bfhv + xfv);
                    size_t c0 = ((size_t)b * nprev + 2 * (nb + p)) * HDIM + col;
                    float fcterm = f0 * b2f(cX[c0]) + f1 * b2f(cX[c0 + HDIM]);
                    cY[((size_t)b * n + nb + p) * HDIM + col] = f2b(fcterm);
                }
            }
        }
    }
}

// ---------------- iou v2 (also leaf): 8 parents/block (M=64), x staged once,
// hsum A-fragments direct from global, zero barriers in K loop.
template <bool LEAF>
__global__ __launch_bounds__(256) void iou_kernel(
    const float* __restrict__ inputs,
    const ushort_t* __restrict__ pWioux, const float* __restrict__ bioux,
    const ushort_t* __restrict__ pWiouh, const float* __restrict__ biouh,
    const ushort_t* __restrict__ hYsum, const ushort_t* __restrict__ cYfc,
    ushort_t* __restrict__ hOut, ushort_t* __restrict__ cOut,
    int start, int n)
{
    const int nb = blockIdx.x * 8;
    const int t = threadIdx.x;
    const int w = t >> 6, lane = t & 63;
    const int kr = lane >> 4, cl = lane & 15;

    __shared__ ushort_t xs[64][344];   // 43 KB, odd bank stride

    for (int idx = t; idx < 64 * 344; idx += 256) {
        int r = idx / 344, k = idx - r * 344;
        int p = r >> 3, b = r & 7;
        int g = start + nb + p;
        float v = (k < INDIM && (nb + p) < n) ? inputs[((size_t)b * NN + g) * INDIM + k] : 0.f;
        xs[r][k] = f2b(v);
    }
    __syncthreads();

    const bf16x8* fWx = reinterpret_cast<const bf16x8*>(pWioux);
    const bf16x8* fWh = reinterpret_cast<const bf16x8*>(pWiouh);

    bool avalid[4]; size_t abase[4];
#pragma unroll
    for (int mt = 0; mt < 4; ++mt) {
        int row = mt * 16 + cl;
        int p = row >> 3, b = row & 7;
        avalid[mt] = (nb + p) < n;
        abase[mt] = ((size_t)b * n + nb + p) * HDIM;
    }

#pragma unroll 1
    for (int j = 0; j < 8; ++j) {
        const int cnt = j * 4 + w;   // 0..31
        f32x4 acc[4][3];             // [mt][q]
#pragma unroll
        for (int mt = 0; mt < 4; ++mt)
#pragma unroll
            for (int q = 0; q < 3; ++q)
#pragma unroll
                for (int r = 0; r < 4; ++r) acc[mt][q][r] = 0.f;

#pragma unroll 2
        for (int kt = 0; kt < 10; ++kt) {
            bf16x8 av[4];
#pragma unroll
            for (int mt = 0; mt < 4; ++mt)
                av[mt] = *reinterpret_cast<const bf16x8*>(&xs[mt * 16 + cl][kt * 32 + kr * 8]);
#pragma unroll
            for (int q = 0; q < 3; ++q) {
                int ntile = q * 32 + cnt;
                bf16x8 bf_ = fWx[(size_t)(ntile * 10 + kt) * 64 + lane];
#pragma unroll
                for (int mt = 0; mt < 4; ++mt)
                    acc[mt][q] = __builtin_amdgcn_mfma_f32_16x16x32_bf16(av[mt], bf_, acc[mt][q], 0, 0, 0);
            }
        }
        if (!LEAF) {
#pragma unroll 2
            for (int kt = 0; kt < 16; ++kt) {
                bf16x8 av[4];
#pragma unroll
                for (int mt = 0; mt < 4; ++mt)
                    av[mt] = avalid[mt]
                        ? *reinterpret_cast<const bf16x8*>(hYsum + abase[mt] + kt * 32 + kr * 8)
                        : zero8();
#pragma unroll
                for (int q = 0; q < 3; ++q) {
                    int ntile = q * 32 + cnt;
                    bf16x8 bf_ = fWh[(size_t)(ntile * 16 + kt) * 64 + lane];
#pragma unroll
                    for (int mt = 0; mt < 4; ++mt)
                        acc[mt][q] = __builtin_amdgcn_mfma_f32_16x16x32_bf16(av[mt], bf_, acc[mt][q], 0, 0, 0);
                }
            }
        }

        const int col = cnt * 16 + cl;
        const float bi = bioux[col]        + biouh[col];
        const float bo = bioux[col + 512]  + biouh[col + 512];
        const float bu = bioux[col + 1024] + biouh[col + 1024];
#pragma unroll
        for (int mt = 0; mt < 4; ++mt) {
#pragma unroll
            for (int r = 0; r < 4; ++r) {
                int row = mt * 16 + kr * 4 + r;
                int p = row >> 3, b = row & 7;
                if (nb + p >= n) continue;
                size_t o = ((size_t)b * n + nb + p) * HDIM + col;
                float fc = LEAF ? 0.f : b2f(cYfc[o]);
                float cv = sigmoidf_(acc[mt][0][r] + bi) * tanhf(acc[mt][2][r] + bu) + fc;
                float hv = sigmoidf_(acc[mt][1][r] + bo) * tanhf(cv);
                hOut[o] = f2b(hv);
                cOut[o] = f2b(cv);
            }
        }
    }
}

// ---------------- output: concat(c_root, h_root) per batch, FP32
__global__ __launch_bounds__(256) void out_kernel(
    const ushort_t* __restrict__ hroot, const ushort_t* __restrict__ croot,
    float* __restrict__ out)
{
    int t = blockIdx.x * 256 + threadIdx.x;
    if (t >= B * 2 * HDIM) return;
    int b = t / (2 * HDIM);
    int j = t - b * 2 * HDIM;
    float v;
    if (j < HDIM) v = b2f(croot[(size_t)b * HDIM + j]);
    else          v = b2f(hroot[(size_t)b * HDIM + (j - HDIM)]);
    out[t] = v;
}

__global__ void diag_kernel(float* out, float v) { out[0] = v; }

extern "C" void kernel_launch(void* const* d_in, const int* in_sizes, int n_in,
                              void* d_out, int out_size, void* d_ws, size_t ws_size,
                              hipStream_t stream)
{
    const float* inputs      = (const float*)d_in[0];
    const float* edge_inputs = (const float*)d_in[1];
    const float* Wioux       = (const float*)d_in[2];
    const float* bioux       = (const float*)d_in[3];
    const float* Wiouh       = (const float*)d_in[4];
    const float* biouh       = (const float*)d_in[5];
    const float* Wfx         = (const float*)d_in[6];
    const float* bfx         = (const float*)d_in[7];
    const float* Wfh         = (const float*)d_in[8];
    const float* bfh         = (const float*)d_in[9];
    const float* We          = (const float*)d_in[10];
    const float* be          = (const float*)d_in[11];
    float* out = (float*)d_out;

    // packed weight element counts (ushort)
    const size_t szWioux = (size_t)96 * 10 * 64 * 8;  // 491520
    const size_t szWfx   = (size_t)32 * 10 * 64 * 8;  // 163840
    const size_t szWe    = (size_t)32 * 4  * 64 * 8;  // 65536
    const size_t szWfh   = (size_t)32 * 16 * 64 * 8;  // 262144
    const size_t szWiouh = (size_t)96 * 16 * 64 * 8;  // 786432

    const size_t eX = (size_t)B * 8192 * HDIM;        // 33,554,432
    const size_t eY = (size_t)B * 4096 * HDIM;        // 16,777,216

    const size_t need = (szWioux + szWfx + szWe + szWfh + szWiouh
                         + 2 * eX + 2 * eY) * sizeof(ushort_t);  // ~204.9 MB
    if (ws_size < need) {
        diag_kernel<<<1, 1, 0, stream>>>(out, 2.0e8f);
        return;
    }

    ushort_t* p = (ushort_t*)d_ws;
    ushort_t* pWioux = p;            p += szWioux;
    ushort_t* pWfx   = p;            p += szWfx;
    ushort_t* pWe    = p;            p += szWe;
    ushort_t* pWfh   = p;            p += szWfh;
    ushort_t* pWiouh = p;            p += szWiouh;
    ushort_t* hX = p;                p += eX;
    ushort_t* cX = p;                p += eX;
    ushort_t* hY = p;                p += eY;
    ushort_t* cY = p;                p += eY;

    // pack weights
    pack_kernel<<<(int)((96 * 10 * 64 + 255) / 256), 256, 0, stream>>>(Wioux, pWioux, INDIM, 10, 96 * 10 * 64);
    pack_kernel<<<(int)((32 * 10 * 64 + 255) / 256), 256, 0, stream>>>(Wfx,   pWfx,   INDIM, 10, 32 * 10 * 64);
    pack_kernel<<<(int)((32 * 4  * 64 + 255) / 256), 256, 0, stream>>>(We,    pWe,    EDIM,  4,  32 * 4  * 64);
    pack_kernel<<<(int)((32 * 16 * 64 + 255) / 256), 256, 0, stream>>>(Wfh,   pWfh,   HDIM,  16, 32 * 16 * 64);
    pack_kernel<<<(int)((96 * 16 * 64 + 255) / 256), 256, 0, stream>>>(Wiouh, pWiouh, HDIM,  16, 96 * 16 * 64);

    // leaf level: start=8191, n=8192
    iou_kernel<true><<<1024, 256, 0, stream>>>(inputs, pWioux, bioux, pWiouh, biouh,
                                               hY, cY, hX, cX, 8191, 8192);

    for (int lvl = 12; lvl >= 0; --lvl) {
        int start = (1 << lvl) - 1;
        int n = 1 << lvl;
        children_kernel<<<(n + 3) / 4, 256, 0, stream>>>(
            inputs, edge_inputs, pWfx, bfx, pWfh, bfh, pWe, be,
            hX, cX, hY, cY, start, n);
        iou_kernel<false><<<(n + 7) / 8, 256, 0, stream>>>(
            inputs, pWioux, bioux, pWiouh, biouh,
            hY, cY, hX, cX, start, n);
    }

    out_kernel<<<(B * 2 * HDIM + 255) / 256, 256, 0, stream>>>(hX, cX, out);
}

// Round 8
// 2842.662 us; speedup vs baseline: 14.5547x; 1.6952x over previous
//
#include <hip/hip_runtime.h>
#include <hip/hip_bf16.h>
#include <stdint.h>

#define B 8
#define NN 16383
#define INDIM 300
#define HDIM 512
#define EDIM 100

typedef short bf16x8 __attribute__((ext_vector_type(8)));
typedef float f32x4 __attribute__((ext_vector_type(4)));
typedef unsigned short ushort_t;

__device__ __forceinline__ float sigmoidf_(float v) { return 1.0f / (1.0f + __expf(-v)); }

__device__ __forceinline__ ushort_t f2b(float f) {
    union { float f; unsigned int u; } x; x.f = f;
    unsigned int u = x.u;
    return (ushort_t)((u + 0x7FFFu + ((u >> 16) & 1u)) >> 16);
}
__device__ __forceinline__ float b2f(ushort_t s) {
    union { float f; unsigned int u; } x; x.u = ((unsigned int)s) << 16; return x.f;
}

// packed h/c layout (K=512): elem (R, col) ->
//   (R>>4)*8192 + (col>>5)*512 + ((col>>3)&3)*128 + (R&15)*8 + (col&7)
__device__ __forceinline__ unsigned int pidx(int R, int col) {
    return (unsigned int)((R >> 4) * 8192 + (col >> 5) * 512 + ((col >> 3) & 3) * 128
                          + (R & 15) * 8 + (col & 7));
}

// swizzled LDS xs (stride 320 ushorts = 640B), frag read 16B
__device__ __forceinline__ bf16x8 xs_frag(const ushort_t* xs, int row, int kt, int kr) {
    unsigned int byte = (unsigned int)(row * 640 + kt * 64 + kr * 16) ^ (unsigned int)((row & 7) << 4);
    return *reinterpret_cast<const bf16x8*>(reinterpret_cast<const char*>(xs) + byte);
}

// ---------------- pack weights into MFMA B-fragment order.
__global__ __launch_bounds__(256) void pack_kernel(
    const float* __restrict__ W, ushort_t* __restrict__ out,
    int Kdim, int Kt, int total)
{
    int idx = blockIdx.x * 256 + threadIdx.x;
    if (idx >= total) return;
    int lane = idx & 63;
    int kt = (idx >> 6) % Kt;
    int nt = idx / (Kt << 6);
    int n = nt * 16 + (lane & 15);
    int kb = kt * 32 + (lane >> 4) * 8;
    ushort_t v[8];
#pragma unroll
    for (int i = 0; i < 8; ++i) {
        int k = kb + i;
        v[i] = (k < Kdim) ? f2b(W[(size_t)n * Kdim + k]) : (ushort_t)0;
    }
    *reinterpret_cast<uint4*>(out + (size_t)idx * 8) = *reinterpret_cast<const uint4*>(v);
}

// ---------------- children v3: 4 parents/block. h/c buffers packed.
// per column-half pp: {xf GEMM -> packed regs; ex GEMM + h_sum epilogue; f GEMM + fc epilogue}
__global__ __launch_bounds__(256) void children_kernel(
    const float* __restrict__ inputs, const float* __restrict__ edge_inputs,
    const ushort_t* __restrict__ pWfx, const float* __restrict__ bfx,
    const ushort_t* __restrict__ pWfh, const float* __restrict__ bfh,
    const ushort_t* __restrict__ pWe,  const float* __restrict__ be,
    const ushort_t* __restrict__ hX, const ushort_t* __restrict__ cX,
    ushort_t* __restrict__ hY, ushort_t* __restrict__ cY,
    int start, int n)
{
    const int nb = blockIdx.x * 4;
    const int t = threadIdx.x;
    const int w = t >> 6, lane = t & 63;
    const int kr = lane >> 4, cl = lane & 15;

    __shared__ ushort_t xs[32 * 320];   // 20 KB, swizzled
    __shared__ ushort_t wc[64][136];    // 17 KB

    // stage x (rows p*8+b, 4 parents)
    for (int i = t; i < 32 * 80; i += 256) {
        int r = i / 80, ch = i - r * 80;
        int p = r >> 3, b = r & 7, k = ch * 4;
        ushort_t vv[4] = {0, 0, 0, 0};
        if (k < INDIM && (nb + p) < n) {
            float4 xv = *reinterpret_cast<const float4*>(
                &inputs[((size_t)b * NN + start + nb + p) * INDIM + k]);
            vv[0] = f2b(xv.x); vv[1] = f2b(xv.y); vv[2] = f2b(xv.z); vv[3] = f2b(xv.w);
        }
        unsigned int byte = (unsigned int)(r * 640 + k * 2) ^ (unsigned int)((r & 7) << 4);
        *reinterpret_cast<uint2*>(reinterpret_cast<char*>(xs) + byte) = *reinterpret_cast<const uint2*>(vv);
    }
    // stage wc (rows kid*32 + p*8 + b)
    for (int i = t; i < 64 * 32; i += 256) {
        int r = i / 32, ch = i - r * 32;
        int kid = r >> 5, pr = r & 31, p = pr >> 3, b = pr & 7;
        int e = ch * 4;
        ushort_t vv[4] = {0, 0, 0, 0};
        if (e < EDIM && (nb + p) < n) {
            float4 xv = *reinterpret_cast<const float4*>(
                &edge_inputs[((size_t)b * NN + 2 * (start + nb + p) + 1 + kid) * EDIM + e]);
            vv[0] = f2b(xv.x); vv[1] = f2b(xv.y); vv[2] = f2b(xv.z); vv[3] = f2b(xv.w);
        }
        *reinterpret_cast<uint2*>(&wc[r][e]) = *reinterpret_cast<const uint2*>(vv);
    }
    __syncthreads();

    const bf16x8* fWfx = reinterpret_cast<const bf16x8*>(pWfx);
    const bf16x8* fWfh = reinterpret_cast<const bf16x8*>(pWfh);
    const bf16x8* fWe  = reinterpret_cast<const bf16x8*>(pWe);

    // per-lane A-frag offsets for f GEMM (tile = parent nb+p, row = 8*kid + b)
    unsigned int cbase[4];
#pragma unroll
    for (int mt = 0; mt < 4; ++mt) {
        int kid = mt >> 1, mh = mt & 1;
        int p = 2 * mh + (cl >> 3);
        int b = cl & 7;
        cbase[mt] = ((nb + p) < n)
            ? (unsigned int)((nb + p) * 8192 + (kr * 16 + 8 * kid + b) * 8)
            : 0u;
    }

#pragma unroll 1
    for (int pp = 0; pp < 2; ++pp) {
        const int ntb = w * 8 + pp * 4;

        // ---- xf GEMM (K=320): rows mh*16+cl
        unsigned int xfp[4][2][2];
        {
            f32x4 xfa[4][2];
#pragma unroll
            for (int q = 0; q < 4; ++q)
#pragma unroll
                for (int mh = 0; mh < 2; ++mh)
#pragma unroll
                    for (int r = 0; r < 4; ++r) xfa[q][mh][r] = 0.f;
#pragma unroll
            for (int kt = 0; kt < 10; ++kt) {
                bf16x8 a0 = xs_frag(xs, cl, kt, kr);
                bf16x8 a1 = xs_frag(xs, 16 + cl, kt, kr);
#pragma unroll
                for (int q = 0; q < 4; ++q) {
                    bf16x8 bf_ = fWfx[(size_t)((ntb + q) * 10 + kt) * 64 + lane];
                    xfa[q][0] = __builtin_amdgcn_mfma_f32_16x16x32_bf16(a0, bf_, xfa[q][0], 0, 0, 0);
                    xfa[q][1] = __builtin_amdgcn_mfma_f32_16x16x32_bf16(a1, bf_, xfa[q][1], 0, 0, 0);
                }
            }
#pragma unroll
            for (int q = 0; q < 4; ++q) {
                float bv = bfx[(ntb + q) * 16 + cl];
#pragma unroll
                for (int mh = 0; mh < 2; ++mh) {
                    xfp[q][mh][0] = ((unsigned int)f2b(xfa[q][mh][1] + bv) << 16) | f2b(xfa[q][mh][0] + bv);
                    xfp[q][mh][1] = ((unsigned int)f2b(xfa[q][mh][3] + bv) << 16) | f2b(xfa[q][mh][2] + bv);
                }
            }
        }

        // ---- ex GEMM (K=128) + h_sum epilogue
        {
            f32x4 eacc[4][4];
#pragma unroll
            for (int q = 0; q < 4; ++q)
#pragma unroll
                for (int mt = 0; mt < 4; ++mt)
#pragma unroll
                    for (int r = 0; r < 4; ++r) eacc[q][mt][r] = 0.f;
#pragma unroll
            for (int kt = 0; kt < 4; ++kt) {
                bf16x8 av[4];
#pragma unroll
                for (int mt = 0; mt < 4; ++mt)
                    av[mt] = *reinterpret_cast<const bf16x8*>(&wc[mt * 16 + cl][kt * 32 + kr * 8]);
#pragma unroll
                for (int q = 0; q < 4; ++q) {
                    bf16x8 bf_ = fWe[(size_t)((ntb + q) * 4 + kt) * 64 + lane];
#pragma unroll
                    for (int mt = 0; mt < 4; ++mt)
                        eacc[q][mt] = __builtin_amdgcn_mfma_f32_16x16x32_bf16(av[mt], bf_, eacc[q][mt], 0, 0, 0);
                }
            }
#pragma unroll
            for (int q = 0; q < 4; ++q) {
                const int col = (ntb + q) * 16 + cl;
                const float bev = be[col];
                const int colc = (col >> 5) * 512 + ((col >> 3) & 3) * 128 + (col & 7);
#pragma unroll
                for (int mh = 0; mh < 2; ++mh) {
#pragma unroll
                    for (int r = 0; r < 4; ++r) {
                        int prow = mh * 16 + kr * 4 + r;
                        int p = prow >> 3, b = prow & 7;
                        if (nb + p >= n) continue;
                        float ex0 = sigmoidf_(eacc[q][mh][r] + bev);
                        float ex1 = sigmoidf_(eacc[q][mh + 2][r] + bev);
                        unsigned int i0 = (unsigned int)((nb + p) * 8192 + colc + b * 8);
                        float hterm = ex0 * b2f(hX[i0]) + ex1 * b2f(hX[i0 + 64]);
                        int Rp = (nb + p) * 8 + b;
                        hY[(unsigned int)((Rp >> 4) * 8192 + colc + (Rp & 15) * 8)] = f2b(hterm);
                    }
                }
            }
        }

        // ---- f GEMM (K=512) + fc epilogue
        {
            f32x4 facc[4][4];
#pragma unroll
            for (int q = 0; q < 4; ++q)
#pragma unroll
                for (int mt = 0; mt < 4; ++mt)
#pragma unroll
                    for (int r = 0; r < 4; ++r) facc[q][mt][r] = 0.f;
#pragma unroll 4
            for (int kt = 0; kt < 16; ++kt) {
                bf16x8 av[4];
#pragma unroll
                for (int mt = 0; mt < 4; ++mt)
                    av[mt] = *reinterpret_cast<const bf16x8*>(hX + cbase[mt] + kt * 512u);
#pragma unroll
                for (int q = 0; q < 4; ++q) {
                    bf16x8 bf_ = fWfh[(size_t)((ntb + q) * 16 + kt) * 64 + lane];
#pragma unroll
                    for (int mt = 0; mt < 4; ++mt)
                        facc[q][mt] = __builtin_amdgcn_mfma_f32_16x16x32_bf16(av[mt], bf_, facc[q][mt], 0, 0, 0);
                }
            }
#pragma unroll
            for (int q = 0; q < 4; ++q) {
                const int col = (ntb + q) * 16 + cl;
                const float bfhv = bfh[col];
                const int colc = (col >> 5) * 512 + ((col >> 3) & 3) * 128 + (col & 7);
#pragma unroll
                for (int mh = 0; mh < 2; ++mh) {
#pragma unroll
                    for (int r = 0; r < 4; ++r) {
                        int prow = mh * 16 + kr * 4 + r;
                        int p = prow >> 3, b = prow & 7;
                        if (nb + p >= n) continue;
                        float xfv = b2f((ushort_t)((xfp[q][mh][r >> 1] >> ((r & 1) * 16)) & 0xffffu));
                        float f0 = sigmoidf_(facc[q][mh][r] + bfhv + xfv);
                        float f1 = sigmoidf_(facc[q][mh + 2][r] + bfhv + xfv);
                        unsigned int i0 = (unsigned int)((nb + p) * 8192 + colc + b * 8);
                        float fcterm = f0 * b2f(cX[i0]) + f1 * b2f(cX[i0 + 64]);
                        int Rp = (nb + p) * 8 + b;
                        cY[(unsigned int)((Rp >> 4) * 8192 + colc + (Rp & 15) * 8)] = f2b(fcterm);
                    }
                }
            }
        }
    }
}

// ---------------- iou v3 (also leaf): 8 parents/block (M=64), packed h_sum frags from global.
template <bool LEAF>
__global__ __launch_bounds__(256) void iou_kernel(
    const float* __restrict__ inputs,
    const ushort_t* __restrict__ pWioux, const float* __restrict__ bioux,
    const ushort_t* __restrict__ pWiouh, const float* __restrict__ biouh,
    const ushort_t* __restrict__ hYsum, const ushort_t* __restrict__ cYfc,
    ushort_t* __restrict__ hOut, ushort_t* __restrict__ cOut,
    int start, int n)
{
    const int nb = blockIdx.x * 8;
    const int t = threadIdx.x;
    const int w = t >> 6, lane = t & 63;
    const int kr = lane >> 4, cl = lane & 15;

    __shared__ ushort_t xs[64 * 320];   // 40 KB, swizzled

    for (int i = t; i < 64 * 80; i += 256) {
        int r = i / 80, ch = i - r * 80;
        int p = r >> 3, b = r & 7, k = ch * 4;
        ushort_t vv[4] = {0, 0, 0, 0};
        if (k < INDIM && (nb + p) < n) {
            float4 xv = *reinterpret_cast<const float4*>(
                &inputs[((size_t)b * NN + start + nb + p) * INDIM + k]);
            vv[0] = f2b(xv.x); vv[1] = f2b(xv.y); vv[2] = f2b(xv.z); vv[3] = f2b(xv.w);
        }
        unsigned int byte = (unsigned int)(r * 640 + k * 2) ^ (unsigned int)((r & 7) << 4);
        *reinterpret_cast<uint2*>(reinterpret_cast<char*>(xs) + byte) = *reinterpret_cast<const uint2*>(vv);
    }
    __syncthreads();

    const bf16x8* fWx = reinterpret_cast<const bf16x8*>(pWioux);
    const bf16x8* fWh = reinterpret_cast<const bf16x8*>(pWiouh);

#pragma unroll 1
    for (int j = 0; j < 8; ++j) {
        const int cnt = j * 4 + w;
        f32x4 acc[4][3];
#pragma unroll
        for (int mt = 0; mt < 4; ++mt)
#pragma unroll
            for (int q = 0; q < 3; ++q)
#pragma unroll
                for (int r = 0; r < 4; ++r) acc[mt][q][r] = 0.f;

#pragma unroll 2
        for (int kt = 0; kt < 10; ++kt) {
            bf16x8 av[4];
#pragma unroll
            for (int mt = 0; mt < 4; ++mt)
                av[mt] = xs_frag(xs, mt * 16 + cl, kt, kr);
#pragma unroll
            for (int q = 0; q < 3; ++q) {
                bf16x8 bf_ = fWx[(size_t)((q * 32 + cnt) * 10 + kt) * 64 + lane];
#pragma unroll
                for (int mt = 0; mt < 4; ++mt)
                    acc[mt][q] = __builtin_amdgcn_mfma_f32_16x16x32_bf16(av[mt], bf_, acc[mt][q], 0, 0, 0);
            }
        }
        if (!LEAF) {
#pragma unroll 4
            for (int kt = 0; kt < 16; ++kt) {
                bf16x8 av[4];
#pragma unroll
                for (int mt = 0; mt < 4; ++mt)
                    av[mt] = *reinterpret_cast<const bf16x8*>(
                        hYsum + (unsigned int)(((nb >> 1) + mt) * 8192 + kt * 512 + lane * 8));
#pragma unroll
                for (int q = 0; q < 3; ++q) {
                    bf16x8 bf_ = fWh[(size_t)((q * 32 + cnt) * 16 + kt) * 64 + lane];
#pragma unroll
                    for (int mt = 0; mt < 4; ++mt)
                        acc[mt][q] = __builtin_amdgcn_mfma_f32_16x16x32_bf16(av[mt], bf_, acc[mt][q], 0, 0, 0);
                }
            }
        }

        const int col = cnt * 16 + cl;
        const float bi = bioux[col]        + biouh[col];
        const float bo = bioux[col + 512]  + biouh[col + 512];
        const float bu = bioux[col + 1024] + biouh[col + 1024];
        const int colc = (col >> 5) * 512 + ((col >> 3) & 3) * 128 + (col & 7);
#pragma unroll
        for (int mt = 0; mt < 4; ++mt) {
#pragma unroll
            for (int r = 0; r < 4; ++r) {
                int row = mt * 16 + kr * 4 + r;
                int p = row >> 3, b = row & 7;
                if (nb + p >= n) continue;
                int R = (nb + p) * 8 + b;
                unsigned int o = (unsigned int)((R >> 4) * 8192 + colc + (R & 15) * 8);
                float fc = LEAF ? 0.f : b2f(cYfc[o]);
                float cv = sigmoidf_(acc[mt][0][r] + bi) * tanhf(acc[mt][2][r] + bu) + fc;
                float hv = sigmoidf_(acc[mt][1][r] + bo) * tanhf(cv);
                hOut[o] = f2b(hv);
                cOut[o] = f2b(cv);
            }
        }
    }
}

// ---------------- output: concat(c_root, h_root) per batch, FP32 (packed-layout read)
__global__ __launch_bounds__(256) void out_kernel(
    const ushort_t* __restrict__ hroot, const ushort_t* __restrict__ croot,
    float* __restrict__ out)
{
    int t = blockIdx.x * 256 + threadIdx.x;
    if (t >= B * 2 * HDIM) return;
    int b = t / (2 * HDIM);
    int j = t - b * 2 * HDIM;
    int col = (j < HDIM) ? j : j - HDIM;
    unsigned int o = pidx(b, col);
    out[t] = (j < HDIM) ? b2f(croot[o]) : b2f(hroot[o]);
}

__global__ void diag_kernel(float* out, float v) { out[0] = v; }

extern "C" void kernel_launch(void* const* d_in, const int* in_sizes, int n_in,
                              void* d_out, int out_size, void* d_ws, size_t ws_size,
                              hipStream_t stream)
{
    const float* inputs      = (const float*)d_in[0];
    const float* edge_inputs = (const float*)d_in[1];
    const float* Wioux       = (const float*)d_in[2];
    const float* bioux       = (const float*)d_in[3];
    const float* Wiouh       = (const float*)d_in[4];
    const float* biouh       = (const float*)d_in[5];
    const float* Wfx         = (const float*)d_in[6];
    const float* bfx         = (const float*)d_in[7];
    const float* Wfh         = (const float*)d_in[8];
    const float* bfh         = (const float*)d_in[9];
    const float* We          = (const float*)d_in[10];
    const float* be          = (const float*)d_in[11];
    float* out = (float*)d_out;

    const size_t szWioux = (size_t)96 * 10 * 64 * 8;
    const size_t szWfx   = (size_t)32 * 10 * 64 * 8;
    const size_t szWe    = (size_t)32 * 4  * 64 * 8;
    const size_t szWfh   = (size_t)32 * 16 * 64 * 8;
    const size_t szWiouh = (size_t)96 * 16 * 64 * 8;

    const size_t eX = (size_t)B * 8192 * HDIM;
    const size_t eY = (size_t)B * 4096 * HDIM;

    const size_t need = (szWioux + szWfx + szWe + szWfh + szWiouh
                         + 2 * eX + 2 * eY) * sizeof(ushort_t);  // ~204.9 MB
    if (ws_size < need) {
        diag_kernel<<<1, 1, 0, stream>>>(out, 2.0e8f);
        return;
    }

    ushort_t* p = (ushort_t*)d_ws;
    ushort_t* pWioux = p;            p += szWioux;
    ushort_t* pWfx   = p;            p += szWfx;
    ushort_t* pWe    = p;            p += szWe;
    ushort_t* pWfh   = p;            p += szWfh;
    ushort_t* pWiouh = p;            p += szWiouh;
    ushort_t* hX = p;                p += eX;
    ushort_t* cX = p;                p += eX;
    ushort_t* hY = p;                p += eY;
    ushort_t* cY = p;                p += eY;

    pack_kernel<<<(96 * 10 * 64 + 255) / 256, 256, 0, stream>>>(Wioux, pWioux, INDIM, 10, 96 * 10 * 64);
    pack_kernel<<<(32 * 10 * 64 + 255) / 256, 256, 0, stream>>>(Wfx,   pWfx,   INDIM, 10, 32 * 10 * 64);
    pack_kernel<<<(32 * 4  * 64 + 255) / 256, 256, 0, stream>>>(We,    pWe,    EDIM,  4,  32 * 4  * 64);
    pack_kernel<<<(32 * 16 * 64 + 255) / 256, 256, 0, stream>>>(Wfh,   pWfh,   HDIM,  16, 32 * 16 * 64);
    pack_kernel<<<(96 * 16 * 64 + 255) / 256, 256, 0, stream>>>(Wiouh, pWiouh, HDIM,  16, 96 * 16 * 64);

    // leaf level: start=8191, n=8192
    iou_kernel<true><<<1024, 256, 0, stream>>>(inputs, pWioux, bioux, pWiouh, biouh,
                                               hY, cY, hX, cX, 8191, 8192);

    for (int lvl = 12; lvl >= 0; --lvl) {
        int start = (1 << lvl) - 1;
        int n = 1 << lvl;
        children_kernel<<<(n + 3) / 4, 256, 0, stream>>>(
            inputs, edge_inputs, pWfx, bfx, pWfh, bfh, pWe, be,
            hX, cX, hY, cY, start, n);
        iou_kernel<false><<<(n + 7) / 8, 256, 0, stream>>>(
            inputs, pWioux, bioux, pWiouh, biouh,
            hY, cY, hX, cX, start, n);
    }

    out_kernel<<<(B * 2 * HDIM + 255) / 256, 256, 0, stream>>>(hX, cX, out);
}